// Round 6
// baseline (2280.325 us; speedup 1.0000x reference)
//
#include <hip/hip_runtime.h>
#include <hip/hip_cooperative_groups.h>

namespace cg = cooperative_groups;

#define NSLOT 32
#define BN_EPS 1e-5f
#define NSB 256             // hist/scatter slices
#define BKBITS 8
#define BKN 256             // nodes per bucket
#define MAXBUCK 512

static inline int cdiv_h(int a, int b) { return (a + b - 1) / b; }

__device__ __forceinline__ float4 f4add(float4 a, float4 b) {
    return make_float4(a.x + b.x, a.y + b.y, a.z + b.z, a.w + b.w);
}

__device__ __forceinline__ unsigned bf16rtn(float x) {
    unsigned u = __float_as_uint(x);
    return (u + 0x7FFFu + ((u >> 16) & 1u)) >> 16;
}
__device__ __forceinline__ unsigned bf16pack2(float lo, float hi) {
    return bf16rtn(lo) | (bf16rtn(hi) << 16);
}
__device__ __forceinline__ float bfLO(unsigned u) { return __uint_as_float(u << 16); }
__device__ __forceinline__ float bfHI(unsigned u) { return __uint_as_float(u & 0xFFFF0000u); }

__device__ __forceinline__ int blk_excl_scan256(int v, int t) {
    __shared__ int wsum[4];
    int l = t & 63, w = t >> 6;
    int incl = v;
#pragma unroll
    for (int off = 1; off < 64; off <<= 1) {
        int o = __shfl_up(incl, off, 64);
        if (l >= off) incl += o;
    }
    if (l == 63) wsum[w] = incl;
    __syncthreads();
    int wofs = 0;
#pragma unroll
    for (int i = 0; i < 4; i++) wofs += (i < w) ? wsum[i] : 0;
    __syncthreads();
    return wofs + incl - v;
}

__device__ __forceinline__ void bn_coef(const float* __restrict__ sSum, const float* __restrict__ sSq,
                                        const float* __restrict__ bg, const float* __restrict__ bb,
                                        float invN, int ch, float* aOut, float* cOut) {
    float S = 0.f, Q = 0.f;
#pragma unroll
    for (int s = 0; s < NSLOT; s++) { S += sSum[s * 32 + ch]; Q += sSq[s * 32 + ch]; }
    float m = S * invN;
    float var = Q * invN - m * m;
    if (var < 0.f) var = 0.f;
    float iv = rsqrtf(var + BN_EPS);
    float a = bg[ch] * iv;
    *aOut = a;
    *cOut = bb[ch] - m * a;
}

union SmU {
    struct { int bins[MAXBUCK]; } hist;
    struct { float sW[32][32]; } t0;
    struct { int sBP[512]; int sTot; int cur[MAXBUCK]; } scat;
    struct { int sBP[512]; int sTot; int binCnt[BKN]; int binStart[BKN]; int cursor[BKN];
             int cellBase[NSB]; int cellCnt[NSB]; } sortb;
    struct { int scol[2112]; float sW[32][32]; float sA[32]; float sC[32];
             float sWS[4][32]; float sWQ[4][32]; } agg;
    struct { float sw[32]; float sA[32]; float sC[32]; float sWS3[4]; float sWQ3[4]; } t3;
    struct { float pcA[128]; float pcC[128]; float sP[8][128]; float sY[4];
             float hg[129]; float hid1[128]; float hid2[64]; } pool;
};

__device__ __forceinline__ void inline_scan512(const int* __restrict__ tot, int* __restrict__ sOut,
                                               int* __restrict__ sTot, int nbuck, int t) {
    int v0 = (t < nbuck) ? tot[t] : 0;
    int v1 = (256 + t < nbuck) ? tot[256 + t] : 0;
    int e0 = blk_excl_scan256(v0, t);
    if (t == 255) *sTot = e0 + v0;
    __syncthreads();
    int e1 = blk_excl_scan256(v1, t) + *sTot;
    sOut[t] = e0;
    sOut[256 + t] = e1;
    __syncthreads();
}

__device__ __forceinline__ void accPlain(float* dst, uint4 v) {
    dst[0] += bfLO(v.x); dst[1] += bfHI(v.x);
    dst[2] += bfLO(v.y); dst[3] += bfHI(v.y);
    dst[4] += bfLO(v.z); dst[5] += bfHI(v.z);
    dst[6] += bfLO(v.w); dst[7] += bfHI(v.w);
}
__device__ __forceinline__ void accAff(float* dst, uint4 v, const float* a8, const float* c8) {
    float x[8] = { bfLO(v.x), bfHI(v.x), bfLO(v.y), bfHI(v.y),
                   bfLO(v.z), bfHI(v.z), bfLO(v.w), bfHI(v.w) };
#pragma unroll
    for (int q = 0; q < 8; q++) { float r = fmaf(a8[q], x[q], c8[q]); dst[q] += r > 0.f ? r : 0.f; }
}

struct KArgs {
    const float* h; const int* src; const int* dst; const int* gid;
    const float* W0; const float* b0c; const float* W1; const float* b1c;
    const float* W2; const float* b2c; const float* w3; const float* b3c;
    const float* bg0; const float* bb0; const float* bg1; const float* bb1;
    const float* bg2; const float* bb2; const float* bg3; const float* bb3;
    const float* mw0; const float* mb0; const float* mw1; const float* mb1;
    const float* mw2; const float* mb2;
    int* histT; int* prefixB; int* totalP; int* totalU;
    unsigned* ebuf; uint4* pb; int* col; int* rs; int* re; int* gstart;
    uint4* y0b; uint4* y1b; uint4* y2b; float* y3;
    float* sSum; float* sSq; float* out;
    int N, E, G, nbuck, chunk, NT64, NT256;
    float invN;
};

// gather+mean tile: MODE 0 = plain mean (+bias); MODE 1 = affine+relu per edge, mean, @W epilogue
template <int MODE>
__device__ void agg_tile(const KArgs& a, SmU& sm, int tile, int t,
                         const uint4* __restrict__ yin, uint4* __restrict__ yout,
                         const float* __restrict__ bias, const float* a8, const float* c8,
                         float* __restrict__ oSum, float* __restrict__ oSq) {
    int lane = t & 3, grp = t >> 2;
    int node0 = tile * 64, node = node0 + grp;
    int base0 = 0, len = 0;
    if (node0 < a.N) {
        int last = node0 + 63; if (last > a.N - 1) last = a.N - 1;
        base0 = a.rs[node0];
        len = a.re[last] - base0;
    }
    bool lds = (len > 0 && len <= 2048);
    if (lds) { for (int i = t; i < len; i += 256) sm.agg.scol[i] = a.col[base0 + i]; }
    __syncthreads();

    float accA[8], accB[8];
#pragma unroll
    for (int q = 0; q < 8; q++) { accA[q] = 0.f; accB[q] = 0.f; }
    float vout[8];
#pragma unroll
    for (int q = 0; q < 8; q++) vout[q] = 0.f;
    int s0 = 0, s1 = 0;
    if (node < a.N) {
        s0 = a.rs[node]; s1 = a.re[node];
#define GATH2(vv, c) vv = yin[(size_t)(c) * 4 + lane]
#define DOACC(d, g) do { if (MODE) accAff(d, g, a8, c8); else accPlain(d, g); } while (0)
        const int* idx = lds ? sm.agg.scol : a.col;
        int j = lds ? s0 - base0 : s0;
        int j1 = lds ? s1 - base0 : s1;
        if (j + 4 <= j1) {
            uint4 g0, g1, g2, g3;
            GATH2(g0, idx[j]); GATH2(g1, idx[j + 1]); GATH2(g2, idx[j + 2]); GATH2(g3, idx[j + 3]);
            j += 4;
            for (; j + 4 <= j1; j += 4) {
                uint4 h0, h1, h2, h3;
                GATH2(h0, idx[j]); GATH2(h1, idx[j + 1]); GATH2(h2, idx[j + 2]); GATH2(h3, idx[j + 3]);
                DOACC(accA, g0); DOACC(accB, g1); DOACC(accA, g2); DOACC(accB, g3);
                g0 = h0; g1 = h1; g2 = h2; g3 = h3;
            }
            DOACC(accA, g0); DOACC(accB, g1); DOACC(accA, g2); DOACC(accB, g3);
        }
        for (; j < j1; ++j) { uint4 g; GATH2(g, idx[j]); DOACC(accA, g); }
#undef GATH2
#undef DOACC
    }
    if (MODE) {
        float* sM = (float*)sm.agg.scol;
        __syncthreads();
        if (node < a.N) {
            int deg = s1 - s0;
            float inv = (deg > 0) ? 1.f / (float)deg : 1.f;
#pragma unroll
            for (int q = 0; q < 8; q++) sM[grp * 33 + lane * 8 + q] = (accA[q] + accB[q]) * inv;
        }
        __syncthreads();
        if (node < a.N) {
            const float4* b4 = (const float4*)bias;
            float4 b0 = b4[lane * 2], b1 = b4[lane * 2 + 1];
            float outv[8] = { b0.x, b0.y, b0.z, b0.w, b1.x, b1.y, b1.z, b1.w };
#pragma unroll
            for (int k = 0; k < 32; k++) {
                float mk = sM[grp * 33 + k];
#pragma unroll
                for (int q = 0; q < 8; q++) outv[q] += mk * sm.agg.sW[k][lane * 8 + q];
            }
#pragma unroll
            for (int q = 0; q < 8; q++) vout[q] = outv[q];
        }
    } else {
        if (node < a.N) {
            int deg = s1 - s0;
            float inv = (deg > 0) ? 1.f / (float)deg : 1.f;
            const float4* b4 = (const float4*)bias;
            float4 b0 = b4[lane * 2], b1 = b4[lane * 2 + 1];
            vout[0] = (accA[0] + accB[0]) * inv + b0.x;
            vout[1] = (accA[1] + accB[1]) * inv + b0.y;
            vout[2] = (accA[2] + accB[2]) * inv + b0.z;
            vout[3] = (accA[3] + accB[3]) * inv + b0.w;
            vout[4] = (accA[4] + accB[4]) * inv + b1.x;
            vout[5] = (accA[5] + accB[5]) * inv + b1.y;
            vout[6] = (accA[6] + accB[6]) * inv + b1.z;
            vout[7] = (accA[7] + accB[7]) * inv + b1.w;
        }
    }
    if (node < a.N) {
        uint4 o;
        o.x = bf16pack2(vout[0], vout[1]);
        o.y = bf16pack2(vout[2], vout[3]);
        o.z = bf16pack2(vout[4], vout[5]);
        o.w = bf16pack2(vout[6], vout[7]);
        yout[(size_t)node * 4 + lane] = o;
    }
    float sqv[8];
#pragma unroll
    for (int q = 0; q < 8; q++) sqv[q] = vout[q] * vout[q];
#pragma unroll
    for (int off = 4; off < 64; off <<= 1) {
#pragma unroll
        for (int q = 0; q < 8; q++) {
            vout[q] += __shfl_xor(vout[q], off, 64);
            sqv[q]  += __shfl_xor(sqv[q],  off, 64);
        }
    }
    int w = t >> 6, l = t & 63;
    if (l < 4) {
#pragma unroll
        for (int q = 0; q < 8; q++) { sm.agg.sWS[w][l * 8 + q] = vout[q]; sm.agg.sWQ[w][l * 8 + q] = sqv[q]; }
    }
    __syncthreads();
    if (t < 32) {
        float S = sm.agg.sWS[0][t] + sm.agg.sWS[1][t] + sm.agg.sWS[2][t] + sm.agg.sWS[3][t];
        float Q = sm.agg.sWQ[0][t] + sm.agg.sWQ[1][t] + sm.agg.sWQ[2][t] + sm.agg.sWQ[3][t];
        int slot = tile & (NSLOT - 1);
        atomicAdd(&oSum[slot * 32 + t], S);
        atomicAdd(&oSq[slot * 32 + t], Q);
    }
}

// ---------------- phase device functions (shared by k_mega and fallback wrappers) ----------------

__device__ void ph1_hist_t0(const KArgs& a, SmU& sm, int bid, int nb, int t) {
    if (bid < NSB) {
        if (bid == 0) {
            for (int i = t; i < 4 * NSLOT * 32; i += 256) { a.sSum[i] = 0.f; a.sSq[i] = 0.f; }
        }
        for (int b = t; b < a.nbuck; b += 256) sm.hist.bins[b] = 0;
        __syncthreads();
        int lo = bid * a.chunk, hi = lo + a.chunk; if (hi > a.E) hi = a.E;
        for (int i = lo + t; i < hi; i += 256) atomicAdd(&sm.hist.bins[a.dst[i] >> BKBITS], 1);
        __syncthreads();
        for (int b = t; b < a.nbuck; b += 256) a.histT[bid * a.nbuck + b] = sm.hist.bins[b];
    } else {
        for (int i = t; i < 1024; i += 256) sm.t0.sW[i >> 5][i & 31] = a.W0[i];
        __syncthreads();
        for (int tile = bid - NSB; tile < a.NT256; tile += nb - NSB) {
            int node = tile * 256 + t;
            if (node < a.N) {
                float x[32];
                const float4* s4 = (const float4*)a.h + (size_t)node * 8;
#pragma unroll
                for (int q = 0; q < 8; q++) {
                    float4 v = s4[q];
                    x[4*q] = v.x; x[4*q+1] = v.y; x[4*q+2] = v.z; x[4*q+3] = v.w;
                }
                float acc[32];
#pragma unroll
                for (int f = 0; f < 32; f++) acc[f] = 0.f;
#pragma unroll
                for (int k = 0; k < 32; k++) {
                    float xv = x[k];
#pragma unroll
                    for (int f = 0; f < 32; f++) acc[f] += xv * sm.t0.sW[k][f];
                }
                uint4* d4 = a.pb + (size_t)node * 4;
#pragma unroll
                for (int q = 0; q < 4; q++) {
                    uint4 o;
                    o.x = bf16pack2(acc[8*q+0], acc[8*q+1]);
                    o.y = bf16pack2(acc[8*q+2], acc[8*q+3]);
                    o.z = bf16pack2(acc[8*q+4], acc[8*q+5]);
                    o.w = bf16pack2(acc[8*q+6], acc[8*q+7]);
                    d4[q] = o;
                }
            }
        }
    }
}

__device__ void ph2_scanA(const KArgs& a, int bid, int nb, int t) {
    for (int b = bid; b < a.nbuck; b += nb) {
        __syncthreads();
        int i = b * 256 + t;
        if (i < a.N) {
            int g = a.gid[i];
            int gp = (i == 0) ? -1 : a.gid[i - 1];
            for (int x = gp + 1; x <= g; ++x) a.gstart[x] = i;
            if (i == a.N - 1) { for (int x = g + 1; x <= a.G; ++x) a.gstart[x] = a.N; }
        }
        int c = a.histT[t * a.nbuck + b];
        int pad = (c + 15) & ~15;
        int ep = blk_excl_scan256(pad, t);
        a.prefixB[b * NSB + t] = ep;
        int ec = blk_excl_scan256(c, t);
        if (t == NSB - 1) { a.totalP[b] = ep + pad; a.totalU[b] = ec + c; }
    }
}

__device__ void ph3_scatter(const KArgs& a, SmU& sm, int bid, int t) {
    if (bid < NSB) {
        inline_scan512(a.totalP, sm.scat.sBP, &sm.scat.sTot, a.nbuck, t);
        for (int b = t; b < a.nbuck; b += 256) sm.scat.cur[b] = sm.scat.sBP[b] + a.prefixB[b * NSB + bid];
        __syncthreads();
        int lo = bid * a.chunk, hi = lo + a.chunk; if (hi > a.E) hi = a.E;
        for (int i = lo + t; i < hi; i += 256) {
            int d = a.dst[i], s = a.src[i];
            int b = d >> BKBITS;
            int pos = atomicAdd(&sm.scat.cur[b], 1);
            a.ebuf[pos] = ((unsigned)(d & (BKN - 1)) << 24) | (unsigned)s;
        }
    }
}

__device__ void ph4_sortb(const KArgs& a, SmU& sm, int bid, int nb, int t) {
    for (int b = bid; b < a.nbuck; b += nb) {
        __syncthreads();
        inline_scan512(a.totalP, sm.sortb.sBP, &sm.sortb.sTot, a.nbuck, t);
        int basePb = sm.sortb.sBP[b];
        __syncthreads();
        inline_scan512(a.totalU, sm.sortb.sBP, &sm.sortb.sTot, a.nbuck, t);
        int baseUb = sm.sortb.sBP[b];
        sm.sortb.cellBase[t] = basePb + a.prefixB[b * NSB + t];
        sm.sortb.cellCnt[t]  = a.histT[t * a.nbuck + b];
        sm.sortb.binCnt[t] = 0; sm.sortb.cursor[t] = 0;
        __syncthreads();
        {
            int cb = sm.sortb.cellBase[t], cc = sm.sortb.cellCnt[t];
            for (int j = 0; j < cc; j++) atomicAdd(&sm.sortb.binCnt[a.ebuf[cb + j] >> 24], 1);
        }
        __syncthreads();
        int bs = blk_excl_scan256(sm.sortb.binCnt[t], t);
        sm.sortb.binStart[t] = bs;
        __syncthreads();
        {
            int cb = sm.sortb.cellBase[t], cc = sm.sortb.cellCnt[t];
            for (int j = 0; j < cc; j++) {
                unsigned e = a.ebuf[cb + j];
                int l = e >> 24;
                int pos = sm.sortb.binStart[l] + atomicAdd(&sm.sortb.cursor[l], 1);
                a.col[baseUb + pos] = (int)(e & 0xFFFFFFu);
            }
        }
        int node = b * BKN + t;
        if (node < a.N) {
            a.rs[node] = baseUb + sm.sortb.binStart[t];
            a.re[node] = baseUb + sm.sortb.binStart[t] + sm.sortb.binCnt[t];
        }
    }
}

__device__ void ph5_agg0(const KArgs& a, SmU& sm, int bid, int nb, int t) {
    for (int tile = bid; tile < a.NT64; tile += nb) {
        __syncthreads();
        agg_tile<0>(a, sm, tile, t, a.pb, a.y0b, a.b0c, nullptr, nullptr,
                    a.sSum + 0 * NSLOT * 32, a.sSq + 0 * NSLOT * 32);
    }
}

__device__ void ph_aggF(const KArgs& a, SmU& sm, int bid, int nb, int t,
                        const uint4* yin, uint4* yout, const float* W, const float* bias,
                        const float* pSum, const float* pSq, const float* bg, const float* bb,
                        float* oSum, float* oSq) {
    for (int i = t; i < 1024; i += 256) sm.agg.sW[i >> 5][i & 31] = W[i];
    if (t < 32) bn_coef(pSum, pSq, bg, bb, a.invN, t, &sm.agg.sA[t], &sm.agg.sC[t]);
    __syncthreads();
    float a8[8], c8[8];
    int lane = t & 3;
#pragma unroll
    for (int q = 0; q < 8; q++) { a8[q] = sm.agg.sA[lane * 8 + q]; c8[q] = sm.agg.sC[lane * 8 + q]; }
    for (int tile = bid; tile < a.NT64; tile += nb) {
        __syncthreads();
        agg_tile<1>(a, sm, tile, t, yin, yout, bias, a8, c8, oSum, oSq);
    }
}

__device__ void ph6_aggF1(const KArgs& a, SmU& sm, int bid, int nb, int t) {
    ph_aggF(a, sm, bid, nb, t, a.y0b, a.y1b, a.W1, a.b1c,
            a.sSum + 0 * NSLOT * 32, a.sSq + 0 * NSLOT * 32, a.bg0, a.bb0,
            a.sSum + 1 * NSLOT * 32, a.sSq + 1 * NSLOT * 32);
}
__device__ void ph7_aggF2(const KArgs& a, SmU& sm, int bid, int nb, int t) {
    ph_aggF(a, sm, bid, nb, t, a.y1b, a.y2b, a.W2, a.b2c,
            a.sSum + 1 * NSLOT * 32, a.sSq + 1 * NSLOT * 32, a.bg1, a.bb1,
            a.sSum + 2 * NSLOT * 32, a.sSq + 2 * NSLOT * 32);
}

__device__ void ph8_t3(const KArgs& a, SmU& sm, int bid, int nb, int t) {
    float* q = (float*)a.pb;         // pb dead after ph5
    if (t < 32) {
        sm.t3.sw[t] = a.w3[t];
        bn_coef(a.sSum + 2 * NSLOT * 32, a.sSq + 2 * NSLOT * 32, a.bg2, a.bb2,
                a.invN, t, &sm.t3.sA[t], &sm.t3.sC[t]);
    }
    __syncthreads();
    for (int tile = bid; tile < a.NT256; tile += nb) {
        int i = tile * 256 + t;
        if (i < a.N) {
            const uint4* x4 = a.y2b + (size_t)i * 4;
            float acc = 0.f;
#pragma unroll
            for (int qq = 0; qq < 4; qq++) {
                uint4 u = x4[qq];
                float vv[8] = { bfLO(u.x), bfHI(u.x), bfLO(u.y), bfHI(u.y),
                                bfLO(u.z), bfHI(u.z), bfLO(u.w), bfHI(u.w) };
#pragma unroll
                for (int r = 0; r < 8; r++) {
                    int k = qq * 8 + r;
                    float xv = sm.t3.sA[k] * vv[r] + sm.t3.sC[k];
                    xv = xv > 0.f ? xv : 0.f;
                    acc += xv * sm.t3.sw[k];
                }
            }
            q[i] = acc;
        }
    }
}

__device__ void ph9_agg3(const KArgs& a, SmU& sm, int bid, int nb, int t) {
    const float* q = (const float*)a.pb;
    for (int tile = bid; tile < a.NT256; tile += nb) {
        __syncthreads();
        int i = tile * 256 + t;
        float lsum = 0.f, lsq = 0.f;
        if (i < a.N) {
            int s0 = a.rs[i], s1 = a.re[i];
            float a0 = 0.f, a1 = 0.f, a2 = 0.f, a3 = 0.f;
            int j = s0;
            if (j + 4 <= s1) {
                float g0 = q[a.col[j]], g1 = q[a.col[j+1]], g2 = q[a.col[j+2]], g3 = q[a.col[j+3]];
                j += 4;
                for (; j + 4 <= s1; j += 4) {
                    float h0 = q[a.col[j]], h1 = q[a.col[j+1]], h2 = q[a.col[j+2]], h3 = q[a.col[j+3]];
                    a0 += g0; a1 += g1; a2 += g2; a3 += g3;
                    g0 = h0; g1 = h1; g2 = h2; g3 = h3;
                }
                a0 += g0; a1 += g1; a2 += g2; a3 += g3;
            }
            for (; j < s1; ++j) a0 += q[a.col[j]];
            float acc = (a0 + a1) + (a2 + a3);
            float inv = (s1 > s0) ? 1.f / (float)(s1 - s0) : 1.f;
            float v = acc * inv + a.b3c[0];
            a.y3[i] = v; lsum = v; lsq = v * v;
        }
#pragma unroll
        for (int off = 1; off < 64; off <<= 1) {
            lsum += __shfl_xor(lsum, off, 64);
            lsq  += __shfl_xor(lsq,  off, 64);
        }
        if ((t & 63) == 0) { sm.t3.sWS3[t >> 6] = lsum; sm.t3.sWQ3[t >> 6] = lsq; }
        __syncthreads();
        if (t == 0) {
            float S = sm.t3.sWS3[0] + sm.t3.sWS3[1] + sm.t3.sWS3[2] + sm.t3.sWS3[3];
            float Q = sm.t3.sWQ3[0] + sm.t3.sWQ3[1] + sm.t3.sWQ3[2] + sm.t3.sWQ3[3];
            int slot = tile & (NSLOT - 1);
            atomicAdd(&a.sSum[3 * NSLOT * 32 + slot * 32], S);
            atomicAdd(&a.sSq[3 * NSLOT * 32 + slot * 32], Q);
        }
    }
}

__device__ void ph10_pool(const KArgs& a, SmU& sm, int bid, int nb, int t) {
    __syncthreads();
    if (t < 97) {
        int layer = (t == 96) ? 3 : (t >> 5);
        int ch = t & 31;
        const float* bg = (layer == 0) ? a.bg0 : (layer == 1) ? a.bg1 : (layer == 2) ? a.bg2 : a.bg3;
        const float* bb = (layer == 0) ? a.bb0 : (layer == 1) ? a.bb1 : (layer == 2) ? a.bb2 : a.bb3;
        bn_coef(a.sSum + layer * NSLOT * 32, a.sSq + layer * NSLOT * 32, bg, bb, a.invN, ch,
                &sm.pool.pcA[t], &sm.pool.pcC[t]);
    }
    __syncthreads();
    int lane = t & 31, slot = t >> 5;
    int arr = lane >> 3, sub = lane & 7;
    const unsigned* yb = (arr == 1) ? (const unsigned*)a.y0b
                       : (arr == 2) ? (const unsigned*)a.y1b : (const unsigned*)a.y2b;
    float4 a4 = make_float4(1.f, 1.f, 1.f, 1.f);
    float4 c4 = make_float4(0.f, 0.f, 0.f, 0.f);
    bool aff = (arr > 0);
    if (aff) {
        a4 = ((const float4*)sm.pool.pcA)[(arr - 1) * 8 + sub];
        c4 = ((const float4*)sm.pool.pcC)[(arr - 1) * 8 + sub];
    }
    float aY = sm.pool.pcA[96], cY = sm.pool.pcC[96];
    for (int g = bid; g < a.G; g += nb) {
        __syncthreads();
        int s0 = a.gstart[g], s1 = a.gstart[g + 1];
        float4 acc = make_float4(0.f, 0.f, 0.f, 0.f);
        for (int n = s0 + slot; n < s1; n += 8) {
            float4 v;
            if (arr == 0) {
                v = ((const float4*)a.h)[(size_t)n * 8 + sub];
            } else {
                uint2 u = ((const uint2*)yb)[(size_t)n * 8 + sub];
                v = make_float4(bfLO(u.x), bfHI(u.x), bfLO(u.y), bfHI(u.y));
            }
            if (aff) {
                float vx = fmaf(a4.x, v.x, c4.x); vx = vx > 0.f ? vx : 0.f;
                float vy = fmaf(a4.y, v.y, c4.y); vy = vy > 0.f ? vy : 0.f;
                float vz = fmaf(a4.z, v.z, c4.z); vz = vz > 0.f ? vz : 0.f;
                float vw = fmaf(a4.w, v.w, c4.w); vw = vw > 0.f ? vw : 0.f;
                v = make_float4(vx, vy, vz, vw);
            }
            acc = f4add(acc, v);
        }
        float ys = 0.f;
        for (int n = s0 + t; n < s1; n += 256) {
            float v = fmaf(aY, a.y3[n], cY);
            ys += v > 0.f ? v : 0.f;
        }
#pragma unroll
        for (int off = 1; off < 64; off <<= 1) ys += __shfl_xor(ys, off, 64);
        if ((t & 63) == 0) sm.pool.sY[t >> 6] = ys;
        ((float4*)&sm.pool.sP[slot][lane * 4])[0] = acc;
        __syncthreads();
        float inv = (s1 > s0) ? 1.f / (float)(s1 - s0) : 1.f;
        if (t < 128) {
            float S = 0.f;
#pragma unroll
            for (int s = 0; s < 8; s++) S += sm.pool.sP[s][t];
            sm.pool.hg[t] = S * inv;
        } else if (t == 128) {
            float S = sm.pool.sY[0] + sm.pool.sY[1] + sm.pool.sY[2] + sm.pool.sY[3];
            sm.pool.hg[128] = S * inv;
        }
        __syncthreads();
        if (t < 128) {
            float v = a.mb0[t];
            for (int i = 0; i < 129; i++) v += sm.pool.hg[i] * a.mw0[i * 128 + t];
            sm.pool.hid1[t] = v > 0.f ? v : 0.f;
        }
        __syncthreads();
        if (t < 64) {
            float v = a.mb1[t];
            for (int i = 0; i < 128; i++) v += sm.pool.hid1[i] * a.mw1[i * 64 + t];
            sm.pool.hid2[t] = v > 0.f ? v : 0.f;
        }
        __syncthreads();
        if (t < 64) {
            float v = sm.pool.hid2[t] * a.mw2[t];
            for (int off = 32; off > 0; off >>= 1) v += __shfl_down(v, off, 64);
            if (t == 0) a.out[g] = v + a.mb2[0];
        }
    }
}

// ---------------- cooperative mega-kernel ----------------

__global__ __launch_bounds__(256, 4) void k_mega(KArgs a) {
    cg::grid_group grid = cg::this_grid();
    __shared__ SmU sm;
    const int t = threadIdx.x, bid = blockIdx.x, nb = gridDim.x;
    ph1_hist_t0(a, sm, bid, nb, t);  __threadfence(); grid.sync();
    ph2_scanA(a, bid, nb, t);        __threadfence(); grid.sync();
    ph3_scatter(a, sm, bid, t);      __threadfence(); grid.sync();
    ph4_sortb(a, sm, bid, nb, t);    __threadfence(); grid.sync();
    ph5_agg0(a, sm, bid, nb, t);     __threadfence(); grid.sync();
    ph6_aggF1(a, sm, bid, nb, t);    __threadfence(); grid.sync();
    ph7_aggF2(a, sm, bid, nb, t);    __threadfence(); grid.sync();
    ph8_t3(a, sm, bid, nb, t);       __threadfence(); grid.sync();
    ph9_agg3(a, sm, bid, nb, t);     __threadfence(); grid.sync();
    ph10_pool(a, sm, bid, nb, t);
}

// ---------------- fallback wrappers (multi-kernel pipeline) ----------------

__global__ __launch_bounds__(256) void k_p1(KArgs a)
{ __shared__ SmU sm; ph1_hist_t0(a, sm, blockIdx.x, gridDim.x, threadIdx.x); }
__global__ __launch_bounds__(256) void k_p2(KArgs a)
{ ph2_scanA(a, blockIdx.x, gridDim.x, threadIdx.x); }
__global__ __launch_bounds__(256) void k_p3(KArgs a)
{ __shared__ SmU sm; ph3_scatter(a, sm, blockIdx.x, threadIdx.x); }
__global__ __launch_bounds__(256) void k_p4(KArgs a)
{ __shared__ SmU sm; ph4_sortb(a, sm, blockIdx.x, gridDim.x, threadIdx.x); }
__global__ __launch_bounds__(256, 6) void k_p5(KArgs a)
{ __shared__ SmU sm; ph5_agg0(a, sm, blockIdx.x, gridDim.x, threadIdx.x); }
__global__ __launch_bounds__(256, 4) void k_p6(KArgs a)
{ __shared__ SmU sm; ph6_aggF1(a, sm, blockIdx.x, gridDim.x, threadIdx.x); }
__global__ __launch_bounds__(256, 4) void k_p7(KArgs a)
{ __shared__ SmU sm; ph7_aggF2(a, sm, blockIdx.x, gridDim.x, threadIdx.x); }
__global__ __launch_bounds__(256) void k_p8(KArgs a)
{ __shared__ SmU sm; ph8_t3(a, sm, blockIdx.x, gridDim.x, threadIdx.x); }
__global__ __launch_bounds__(256) void k_p9(KArgs a)
{ __shared__ SmU sm; ph9_agg3(a, sm, blockIdx.x, gridDim.x, threadIdx.x); }
__global__ __launch_bounds__(256) void k_p10(KArgs a)
{ __shared__ SmU sm; ph10_pool(a, sm, blockIdx.x, gridDim.x, threadIdx.x); }

// ---------------- launcher ----------------

extern "C" void kernel_launch(void* const* d_in, const int* in_sizes, int n_in,
                              void* d_out, int out_size, void* d_ws, size_t ws_size,
                              hipStream_t stream) {
    KArgs ka;
    ka.h   = (const float*)d_in[0];
    ka.src = (const int*)d_in[1];
    ka.dst = (const int*)d_in[2];
    ka.gid = (const int*)d_in[3];
    const float* convw[4], *convb[4], *bng[4], *bnb[4];
    for (int i = 0; i < 4; i++) {
        convw[i] = (const float*)d_in[4 + 4 * i];
        convb[i] = (const float*)d_in[5 + 4 * i];
        bng[i]   = (const float*)d_in[6 + 4 * i];
        bnb[i]   = (const float*)d_in[7 + 4 * i];
    }
    ka.W0 = convw[0]; ka.b0c = convb[0]; ka.W1 = convw[1]; ka.b1c = convb[1];
    ka.W2 = convw[2]; ka.b2c = convb[2]; ka.w3 = convw[3]; ka.b3c = convb[3];
    ka.bg0 = bng[0]; ka.bb0 = bnb[0]; ka.bg1 = bng[1]; ka.bb1 = bnb[1];
    ka.bg2 = bng[2]; ka.bb2 = bnb[2]; ka.bg3 = bng[3]; ka.bb3 = bnb[3];
    ka.mw0 = (const float*)d_in[20]; ka.mb0 = (const float*)d_in[21];
    ka.mw1 = (const float*)d_in[22]; ka.mb1 = (const float*)d_in[23];
    ka.mw2 = (const float*)d_in[24]; ka.mb2 = (const float*)d_in[25];

    const int N = in_sizes[0] / 32;
    const int E = in_sizes[1];
    const int G = out_size;
    const int nbuck = cdiv_h(N, BKN);
    const int chunk = cdiv_h(E, NSB);

    char* ws = (char*)d_ws;
    size_t off = 0;
    auto alloc = [&](size_t bytes) -> void* {
        void* p = ws + off;
        off += (bytes + 511) & ~(size_t)511;
        return p;
    };
    ka.histT   = (int*)alloc((size_t)NSB * nbuck * 4);
    ka.prefixB = (int*)alloc((size_t)nbuck * NSB * 4);
    ka.totalP  = (int*)alloc((size_t)nbuck * 4);
    ka.totalU  = (int*)alloc((size_t)nbuck * 4);
    size_t ebufE = (size_t)E + (size_t)16 * NSB * nbuck;
    ka.ebuf = (unsigned*)alloc(ebufE * 4);
    ka.pb   = (uint4*)alloc((size_t)N * 64);     // reused as fp32 q in ph8/ph9
    ka.col  = (int*)alloc((size_t)E * 4);
    ka.rs   = (int*)alloc((size_t)N * 4);
    ka.re   = (int*)alloc((size_t)N * 4);
    ka.gstart = (int*)alloc((size_t)(G + 1) * 4);
    ka.y0b  = (uint4*)alloc((size_t)N * 64);
    ka.y1b  = (uint4*)alloc((size_t)N * 64);
    ka.y2b  = (uint4*)alloc((size_t)N * 64);
    ka.y3   = (float*)alloc((size_t)N * 4);
    ka.sSum = (float*)alloc((size_t)4 * NSLOT * 32 * 4);
    ka.sSq  = (float*)alloc((size_t)4 * NSLOT * 32 * 4);
    ka.out  = (float*)d_out;
    (void)ws_size; (void)n_in;

    ka.N = N; ka.E = E; ka.G = G; ka.nbuck = nbuck; ka.chunk = chunk;
    ka.NT64 = cdiv_h(N, 64); ka.NT256 = cdiv_h(N, 256);
    ka.invN = 1.f / (float)N;

    void* params[] = { (void*)&ka };
    static const int ladder[4] = { 1024, 768, 512, 384 };   // all > NSB so ph1's t0 blocks exist
    hipError_t e = hipErrorUnknown;
    for (int i = 0; i < 4 && e != hipSuccess; i++) {
        e = hipLaunchCooperativeKernel((const void*)k_mega, dim3(ladder[i]), dim3(256), params, 0, stream);
        if (e != hipSuccess) (void)hipGetLastError();   // clear sticky error before retry/fallback
    }
    if (e != hipSuccess) {
        // fallback: known-good 10-dispatch pipeline
        k_p1<<<NSB + ka.NT256, 256, 0, stream>>>(ka);
        k_p2<<<nbuck, 256, 0, stream>>>(ka);
        k_p3<<<NSB, 256, 0, stream>>>(ka);
        k_p4<<<nbuck, 256, 0, stream>>>(ka);
        k_p5<<<ka.NT64, 256, 0, stream>>>(ka);
        k_p6<<<ka.NT64, 256, 0, stream>>>(ka);
        k_p7<<<ka.NT64, 256, 0, stream>>>(ka);
        k_p8<<<ka.NT256, 256, 0, stream>>>(ka);
        k_p9<<<ka.NT256, 256, 0, stream>>>(ka);
        k_p10<<<G, 256, 0, stream>>>(ka);
    }
}

// Round 7
// 2242.593 us; speedup vs baseline: 1.0168x; 1.0168x over previous
//
#include <hip/hip_runtime.h>
#include <hip/hip_cooperative_groups.h>

namespace cg = cooperative_groups;

#define NSLOT 32
#define BN_EPS 1e-5f
#define NSB 256             // hist/scatter slices
#define BKBITS 8
#define BKN 256             // nodes per bucket
#define MAXBUCK 512

static inline int cdiv_h(int a, int b) { return (a + b - 1) / b; }

__device__ __forceinline__ float4 f4add(float4 a, float4 b) {
    return make_float4(a.x + b.x, a.y + b.y, a.z + b.z, a.w + b.w);
}

__device__ __forceinline__ unsigned bf16rtn(float x) {
    unsigned u = __float_as_uint(x);
    return (u + 0x7FFFu + ((u >> 16) & 1u)) >> 16;
}
__device__ __forceinline__ unsigned bf16pack2(float lo, float hi) {
    return bf16rtn(lo) | (bf16rtn(hi) << 16);
}
__device__ __forceinline__ float bfLO(unsigned u) { return __uint_as_float(u << 16); }
__device__ __forceinline__ float bfHI(unsigned u) { return __uint_as_float(u & 0xFFFF0000u); }

__device__ __forceinline__ int blk_excl_scan256(int v, int t) {
    __shared__ int wsum[4];
    int l = t & 63, w = t >> 6;
    int incl = v;
#pragma unroll
    for (int off = 1; off < 64; off <<= 1) {
        int o = __shfl_up(incl, off, 64);
        if (l >= off) incl += o;
    }
    if (l == 63) wsum[w] = incl;
    __syncthreads();
    int wofs = 0;
#pragma unroll
    for (int i = 0; i < 4; i++) wofs += (i < w) ? wsum[i] : 0;
    __syncthreads();
    return wofs + incl - v;
}

__device__ __forceinline__ void bn_coef(const float* __restrict__ sSum, const float* __restrict__ sSq,
                                        const float* __restrict__ bg, const float* __restrict__ bb,
                                        float invN, int ch, float* aOut, float* cOut) {
    float S = 0.f, Q = 0.f;
#pragma unroll
    for (int s = 0; s < NSLOT; s++) { S += sSum[s * 32 + ch]; Q += sSq[s * 32 + ch]; }
    float m = S * invN;
    float var = Q * invN - m * m;
    if (var < 0.f) var = 0.f;
    float iv = rsqrtf(var + BN_EPS);
    float a = bg[ch] * iv;
    *aOut = a;
    *cOut = bb[ch] - m * a;
}

union SmU {
    struct { int bins[MAXBUCK]; } hist;
    struct { float sW[32][32]; } t0;
    struct { int sBP[512]; int sTot; int cur[MAXBUCK]; } scat;
    struct { int sBP[512]; int sTot; int binCnt[BKN]; int binStart[BKN]; int cursor[BKN];
             int cellBase[NSB]; int cellCnt[NSB]; } sortb;
    struct { int scol[2112]; float sW[32][32]; float sA[32]; float sC[32];
             float sWS[4][32]; float sWQ[4][32]; } agg;
    struct { float sw[32]; float sA[32]; float sC[32]; float sWS3[4]; float sWQ3[4]; } t3;
    struct { float pcA[128]; float pcC[128]; float sP[8][128]; float sY[4];
             float hg[129]; float hid1[128]; float hid2[64]; } pool;
};

__device__ __forceinline__ void inline_scan512(const int* __restrict__ tot, int* __restrict__ sOut,
                                               int* __restrict__ sTot, int nbuck, int t) {
    int v0 = (t < nbuck) ? tot[t] : 0;
    int v1 = (256 + t < nbuck) ? tot[256 + t] : 0;
    int e0 = blk_excl_scan256(v0, t);
    if (t == 255) *sTot = e0 + v0;
    __syncthreads();
    int e1 = blk_excl_scan256(v1, t) + *sTot;
    sOut[t] = e0;
    sOut[256 + t] = e1;
    __syncthreads();
}

__device__ __forceinline__ void accPlain(float* dst, uint4 v) {
    dst[0] += bfLO(v.x); dst[1] += bfHI(v.x);
    dst[2] += bfLO(v.y); dst[3] += bfHI(v.y);
    dst[4] += bfLO(v.z); dst[5] += bfHI(v.z);
    dst[6] += bfLO(v.w); dst[7] += bfHI(v.w);
}
__device__ __forceinline__ void accAff(float* dst, uint4 v, const float* a8, const float* c8) {
    float x[8] = { bfLO(v.x), bfHI(v.x), bfLO(v.y), bfHI(v.y),
                   bfLO(v.z), bfHI(v.z), bfLO(v.w), bfHI(v.w) };
#pragma unroll
    for (int q = 0; q < 8; q++) { float r = fmaf(a8[q], x[q], c8[q]); dst[q] += r > 0.f ? r : 0.f; }
}

struct KArgs {
    const float* h; const int* src; const int* dst; const int* gid;
    const float* W0; const float* b0c; const float* W1; const float* b1c;
    const float* W2; const float* b2c; const float* w3; const float* b3c;
    const float* bg0; const float* bb0; const float* bg1; const float* bb1;
    const float* bg2; const float* bb2; const float* bg3; const float* bb3;
    const float* mw0; const float* mb0; const float* mw1; const float* mb1;
    const float* mw2; const float* mb2;
    int* histT; int* prefixB; int* totalP; int* totalU;
    unsigned* ebuf; uint4* pb; int* col; int* rs; int* re; int* gstart;
    uint4* y0b; uint4* y1b; uint4* y2b; float* y3;
    float* sSum; float* sSq; float* out;
    int N, E, G, nbuck, chunk, NT64, NT256;
    float invN;
};

// gather+mean tile: MODE 0 = plain mean (+bias); MODE 1 = affine+relu per edge, mean, @W epilogue
template <int MODE>
__device__ __forceinline__ void agg_tile(const KArgs& a, SmU& sm, int tile, int t,
                         const uint4* __restrict__ yin, uint4* __restrict__ yout,
                         const float* __restrict__ bias, const float* a8, const float* c8,
                         float* __restrict__ oSum, float* __restrict__ oSq) {
    int lane = t & 3, grp = t >> 2;
    int node0 = tile * 64, node = node0 + grp;
    int base0 = 0, len = 0;
    if (node0 < a.N) {
        int last = node0 + 63; if (last > a.N - 1) last = a.N - 1;
        base0 = a.rs[node0];
        len = a.re[last] - base0;
    }
    bool lds = (len > 0 && len <= 2048);
    if (lds) { for (int i = t; i < len; i += 256) sm.agg.scol[i] = a.col[base0 + i]; }
    __syncthreads();

    float accA[8], accB[8];
#pragma unroll
    for (int q = 0; q < 8; q++) { accA[q] = 0.f; accB[q] = 0.f; }
    float vout[8];
#pragma unroll
    for (int q = 0; q < 8; q++) vout[q] = 0.f;
    int s0 = 0, s1 = 0;
    if (node < a.N) {
        s0 = a.rs[node]; s1 = a.re[node];
#define GATH2(vv, c) vv = yin[(size_t)(c) * 4 + lane]
#define DOACC(d, g) do { if (MODE) accAff(d, g, a8, c8); else accPlain(d, g); } while (0)
        const int* idx = lds ? sm.agg.scol : a.col;
        int j = lds ? s0 - base0 : s0;
        int j1 = lds ? s1 - base0 : s1;
        if (j + 4 <= j1) {
            uint4 g0, g1, g2, g3;
            GATH2(g0, idx[j]); GATH2(g1, idx[j + 1]); GATH2(g2, idx[j + 2]); GATH2(g3, idx[j + 3]);
            j += 4;
            for (; j + 4 <= j1; j += 4) {
                uint4 h0, h1, h2, h3;
                GATH2(h0, idx[j]); GATH2(h1, idx[j + 1]); GATH2(h2, idx[j + 2]); GATH2(h3, idx[j + 3]);
                DOACC(accA, g0); DOACC(accB, g1); DOACC(accA, g2); DOACC(accB, g3);
                g0 = h0; g1 = h1; g2 = h2; g3 = h3;
            }
            DOACC(accA, g0); DOACC(accB, g1); DOACC(accA, g2); DOACC(accB, g3);
        }
        for (; j < j1; ++j) { uint4 g; GATH2(g, idx[j]); DOACC(accA, g); }
#undef GATH2
#undef DOACC
    }
    if (MODE) {
        float* sM = (float*)sm.agg.scol;
        __syncthreads();
        if (node < a.N) {
            int deg = s1 - s0;
            float inv = (deg > 0) ? 1.f / (float)deg : 1.f;
#pragma unroll
            for (int q = 0; q < 8; q++) sM[grp * 33 + lane * 8 + q] = (accA[q] + accB[q]) * inv;
        }
        __syncthreads();
        if (node < a.N) {
            const float4* b4 = (const float4*)bias;
            float4 b0 = b4[lane * 2], b1 = b4[lane * 2 + 1];
            float outv[8] = { b0.x, b0.y, b0.z, b0.w, b1.x, b1.y, b1.z, b1.w };
#pragma unroll
            for (int k = 0; k < 32; k++) {
                float mk = sM[grp * 33 + k];
#pragma unroll
                for (int q = 0; q < 8; q++) outv[q] += mk * sm.agg.sW[k][lane * 8 + q];
            }
#pragma unroll
            for (int q = 0; q < 8; q++) vout[q] = outv[q];
        }
    } else {
        if (node < a.N) {
            int deg = s1 - s0;
            float inv = (deg > 0) ? 1.f / (float)deg : 1.f;
            const float4* b4 = (const float4*)bias;
            float4 b0 = b4[lane * 2], b1 = b4[lane * 2 + 1];
            vout[0] = (accA[0] + accB[0]) * inv + b0.x;
            vout[1] = (accA[1] + accB[1]) * inv + b0.y;
            vout[2] = (accA[2] + accB[2]) * inv + b0.z;
            vout[3] = (accA[3] + accB[3]) * inv + b0.w;
            vout[4] = (accA[4] + accB[4]) * inv + b1.x;
            vout[5] = (accA[5] + accB[5]) * inv + b1.y;
            vout[6] = (accA[6] + accB[6]) * inv + b1.z;
            vout[7] = (accA[7] + accB[7]) * inv + b1.w;
        }
    }
    if (node < a.N) {
        uint4 o;
        o.x = bf16pack2(vout[0], vout[1]);
        o.y = bf16pack2(vout[2], vout[3]);
        o.z = bf16pack2(vout[4], vout[5]);
        o.w = bf16pack2(vout[6], vout[7]);
        yout[(size_t)node * 4 + lane] = o;
    }
    float sqv[8];
#pragma unroll
    for (int q = 0; q < 8; q++) sqv[q] = vout[q] * vout[q];
#pragma unroll
    for (int off = 4; off < 64; off <<= 1) {
#pragma unroll
        for (int q = 0; q < 8; q++) {
            vout[q] += __shfl_xor(vout[q], off, 64);
            sqv[q]  += __shfl_xor(sqv[q],  off, 64);
        }
    }
    int w = t >> 6, l = t & 63;
    if (l < 4) {
#pragma unroll
        for (int q = 0; q < 8; q++) { sm.agg.sWS[w][l * 8 + q] = vout[q]; sm.agg.sWQ[w][l * 8 + q] = sqv[q]; }
    }
    __syncthreads();
    if (t < 32) {
        float S = sm.agg.sWS[0][t] + sm.agg.sWS[1][t] + sm.agg.sWS[2][t] + sm.agg.sWS[3][t];
        float Q = sm.agg.sWQ[0][t] + sm.agg.sWQ[1][t] + sm.agg.sWQ[2][t] + sm.agg.sWQ[3][t];
        int slot = tile & (NSLOT - 1);
        atomicAdd(&oSum[slot * 32 + t], S);
        atomicAdd(&oSq[slot * 32 + t], Q);
    }
}

// ---------------- phase device functions (ALL forceinline: keeps KArgs in SGPRs, no scratch) ----

__device__ __forceinline__ void ph1_hist_t0(const KArgs& a, SmU& sm, int bid, int nb, int t) {
    if (bid < NSB) {
        if (bid == 0) {
            for (int i = t; i < 4 * NSLOT * 32; i += 256) { a.sSum[i] = 0.f; a.sSq[i] = 0.f; }
        }
        for (int b = t; b < a.nbuck; b += 256) sm.hist.bins[b] = 0;
        __syncthreads();
        int lo = bid * a.chunk, hi = lo + a.chunk; if (hi > a.E) hi = a.E;
        for (int i = lo + t; i < hi; i += 256) atomicAdd(&sm.hist.bins[a.dst[i] >> BKBITS], 1);
        __syncthreads();
        for (int b = t; b < a.nbuck; b += 256) a.histT[bid * a.nbuck + b] = sm.hist.bins[b];
    } else {
        for (int i = t; i < 1024; i += 256) sm.t0.sW[i >> 5][i & 31] = a.W0[i];
        __syncthreads();
        for (int tile = bid - NSB; tile < a.NT256; tile += nb - NSB) {
            int node = tile * 256 + t;
            if (node < a.N) {
                float x[32];
                const float4* s4 = (const float4*)a.h + (size_t)node * 8;
#pragma unroll
                for (int q = 0; q < 8; q++) {
                    float4 v = s4[q];
                    x[4*q] = v.x; x[4*q+1] = v.y; x[4*q+2] = v.z; x[4*q+3] = v.w;
                }
                float acc[32];
#pragma unroll
                for (int f = 0; f < 32; f++) acc[f] = 0.f;
#pragma unroll
                for (int k = 0; k < 32; k++) {
                    float xv = x[k];
#pragma unroll
                    for (int f = 0; f < 32; f++) acc[f] += xv * sm.t0.sW[k][f];
                }
                uint4* d4 = a.pb + (size_t)node * 4;
#pragma unroll
                for (int q = 0; q < 4; q++) {
                    uint4 o;
                    o.x = bf16pack2(acc[8*q+0], acc[8*q+1]);
                    o.y = bf16pack2(acc[8*q+2], acc[8*q+3]);
                    o.z = bf16pack2(acc[8*q+4], acc[8*q+5]);
                    o.w = bf16pack2(acc[8*q+6], acc[8*q+7]);
                    d4[q] = o;
                }
            }
        }
    }
}

__device__ __forceinline__ void ph2_scanA(const KArgs& a, int bid, int nb, int t) {
    for (int b = bid; b < a.nbuck; b += nb) {
        __syncthreads();
        int i = b * 256 + t;
        if (i < a.N) {
            int g = a.gid[i];
            int gp = (i == 0) ? -1 : a.gid[i - 1];
            for (int x = gp + 1; x <= g; ++x) a.gstart[x] = i;
            if (i == a.N - 1) { for (int x = g + 1; x <= a.G; ++x) a.gstart[x] = a.N; }
        }
        int c = a.histT[t * a.nbuck + b];
        int pad = (c + 15) & ~15;
        int ep = blk_excl_scan256(pad, t);
        a.prefixB[b * NSB + t] = ep;
        int ec = blk_excl_scan256(c, t);
        if (t == NSB - 1) { a.totalP[b] = ep + pad; a.totalU[b] = ec + c; }
    }
}

__device__ __forceinline__ void ph3_scatter(const KArgs& a, SmU& sm, int bid, int t) {
    if (bid < NSB) {
        inline_scan512(a.totalP, sm.scat.sBP, &sm.scat.sTot, a.nbuck, t);
        for (int b = t; b < a.nbuck; b += 256) sm.scat.cur[b] = sm.scat.sBP[b] + a.prefixB[b * NSB + bid];
        __syncthreads();
        int lo = bid * a.chunk, hi = lo + a.chunk; if (hi > a.E) hi = a.E;
        for (int i = lo + t; i < hi; i += 256) {
            int d = a.dst[i], s = a.src[i];
            int b = d >> BKBITS;
            int pos = atomicAdd(&sm.scat.cur[b], 1);
            a.ebuf[pos] = ((unsigned)(d & (BKN - 1)) << 24) | (unsigned)s;
        }
    }
}

__device__ __forceinline__ void ph4_sortb(const KArgs& a, SmU& sm, int bid, int nb, int t) {
    for (int b = bid; b < a.nbuck; b += nb) {
        __syncthreads();
        inline_scan512(a.totalP, sm.sortb.sBP, &sm.sortb.sTot, a.nbuck, t);
        int basePb = sm.sortb.sBP[b];
        __syncthreads();
        inline_scan512(a.totalU, sm.sortb.sBP, &sm.sortb.sTot, a.nbuck, t);
        int baseUb = sm.sortb.sBP[b];
        sm.sortb.cellBase[t] = basePb + a.prefixB[b * NSB + t];
        sm.sortb.cellCnt[t]  = a.histT[t * a.nbuck + b];
        sm.sortb.binCnt[t] = 0; sm.sortb.cursor[t] = 0;
        __syncthreads();
        {
            int cb = sm.sortb.cellBase[t], cc = sm.sortb.cellCnt[t];
            for (int j = 0; j < cc; j++) atomicAdd(&sm.sortb.binCnt[a.ebuf[cb + j] >> 24], 1);
        }
        __syncthreads();
        int bs = blk_excl_scan256(sm.sortb.binCnt[t], t);
        sm.sortb.binStart[t] = bs;
        __syncthreads();
        {
            int cb = sm.sortb.cellBase[t], cc = sm.sortb.cellCnt[t];
            for (int j = 0; j < cc; j++) {
                unsigned e = a.ebuf[cb + j];
                int l = e >> 24;
                int pos = sm.sortb.binStart[l] + atomicAdd(&sm.sortb.cursor[l], 1);
                a.col[baseUb + pos] = (int)(e & 0xFFFFFFu);
            }
        }
        int node = b * BKN + t;
        if (node < a.N) {
            a.rs[node] = baseUb + sm.sortb.binStart[t];
            a.re[node] = baseUb + sm.sortb.binStart[t] + sm.sortb.binCnt[t];
        }
    }
}

__device__ __forceinline__ void ph5_agg0(const KArgs& a, SmU& sm, int bid, int nb, int t) {
    for (int tile = bid; tile < a.NT64; tile += nb) {
        __syncthreads();
        agg_tile<0>(a, sm, tile, t, a.pb, a.y0b, a.b0c, nullptr, nullptr,
                    a.sSum + 0 * NSLOT * 32, a.sSq + 0 * NSLOT * 32);
    }
}

__device__ __forceinline__ void ph_aggF(const KArgs& a, SmU& sm, int bid, int nb, int t,
                        const uint4* yin, uint4* yout, const float* W, const float* bias,
                        const float* pSum, const float* pSq, const float* bg, const float* bb,
                        float* oSum, float* oSq) {
    for (int i = t; i < 1024; i += 256) sm.agg.sW[i >> 5][i & 31] = W[i];
    if (t < 32) bn_coef(pSum, pSq, bg, bb, a.invN, t, &sm.agg.sA[t], &sm.agg.sC[t]);
    __syncthreads();
    float a8[8], c8[8];
    int lane = t & 3;
#pragma unroll
    for (int q = 0; q < 8; q++) { a8[q] = sm.agg.sA[lane * 8 + q]; c8[q] = sm.agg.sC[lane * 8 + q]; }
    for (int tile = bid; tile < a.NT64; tile += nb) {
        __syncthreads();
        agg_tile<1>(a, sm, tile, t, yin, yout, bias, a8, c8, oSum, oSq);
    }
}

__device__ __forceinline__ void ph6_aggF1(const KArgs& a, SmU& sm, int bid, int nb, int t) {
    ph_aggF(a, sm, bid, nb, t, a.y0b, a.y1b, a.W1, a.b1c,
            a.sSum + 0 * NSLOT * 32, a.sSq + 0 * NSLOT * 32, a.bg0, a.bb0,
            a.sSum + 1 * NSLOT * 32, a.sSq + 1 * NSLOT * 32);
}
__device__ __forceinline__ void ph7_aggF2(const KArgs& a, SmU& sm, int bid, int nb, int t) {
    ph_aggF(a, sm, bid, nb, t, a.y1b, a.y2b, a.W2, a.b2c,
            a.sSum + 1 * NSLOT * 32, a.sSq + 1 * NSLOT * 32, a.bg1, a.bb1,
            a.sSum + 2 * NSLOT * 32, a.sSq + 2 * NSLOT * 32);
}

__device__ __forceinline__ void ph8_t3(const KArgs& a, SmU& sm, int bid, int nb, int t) {
    float* q = (float*)a.pb;         // pb dead after ph5
    if (t < 32) {
        sm.t3.sw[t] = a.w3[t];
        bn_coef(a.sSum + 2 * NSLOT * 32, a.sSq + 2 * NSLOT * 32, a.bg2, a.bb2,
                a.invN, t, &sm.t3.sA[t], &sm.t3.sC[t]);
    }
    __syncthreads();
    for (int tile = bid; tile < a.NT256; tile += nb) {
        int i = tile * 256 + t;
        if (i < a.N) {
            const uint4* x4 = a.y2b + (size_t)i * 4;
            float acc = 0.f;
#pragma unroll
            for (int qq = 0; qq < 4; qq++) {
                uint4 u = x4[qq];
                float vv[8] = { bfLO(u.x), bfHI(u.x), bfLO(u.y), bfHI(u.y),
                                bfLO(u.z), bfHI(u.z), bfLO(u.w), bfHI(u.w) };
#pragma unroll
                for (int r = 0; r < 8; r++) {
                    int k = qq * 8 + r;
                    float xv = sm.t3.sA[k] * vv[r] + sm.t3.sC[k];
                    xv = xv > 0.f ? xv : 0.f;
                    acc += xv * sm.t3.sw[k];
                }
            }
            q[i] = acc;
        }
    }
}

__device__ __forceinline__ void ph9_agg3(const KArgs& a, SmU& sm, int bid, int nb, int t) {
    const float* q = (const float*)a.pb;
    for (int tile = bid; tile < a.NT256; tile += nb) {
        __syncthreads();
        int i = tile * 256 + t;
        float lsum = 0.f, lsq = 0.f;
        if (i < a.N) {
            int s0 = a.rs[i], s1 = a.re[i];
            float a0 = 0.f, a1 = 0.f, a2 = 0.f, a3 = 0.f;
            int j = s0;
            if (j + 4 <= s1) {
                float g0 = q[a.col[j]], g1 = q[a.col[j+1]], g2 = q[a.col[j+2]], g3 = q[a.col[j+3]];
                j += 4;
                for (; j + 4 <= s1; j += 4) {
                    float h0 = q[a.col[j]], h1 = q[a.col[j+1]], h2 = q[a.col[j+2]], h3 = q[a.col[j+3]];
                    a0 += g0; a1 += g1; a2 += g2; a3 += g3;
                    g0 = h0; g1 = h1; g2 = h2; g3 = h3;
                }
                a0 += g0; a1 += g1; a2 += g2; a3 += g3;
            }
            for (; j < s1; ++j) a0 += q[a.col[j]];
            float acc = (a0 + a1) + (a2 + a3);
            float inv = (s1 > s0) ? 1.f / (float)(s1 - s0) : 1.f;
            float v = acc * inv + a.b3c[0];
            a.y3[i] = v; lsum = v; lsq = v * v;
        }
#pragma unroll
        for (int off = 1; off < 64; off <<= 1) {
            lsum += __shfl_xor(lsum, off, 64);
            lsq  += __shfl_xor(lsq,  off, 64);
        }
        if ((t & 63) == 0) { sm.t3.sWS3[t >> 6] = lsum; sm.t3.sWQ3[t >> 6] = lsq; }
        __syncthreads();
        if (t == 0) {
            float S = sm.t3.sWS3[0] + sm.t3.sWS3[1] + sm.t3.sWS3[2] + sm.t3.sWS3[3];
            float Q = sm.t3.sWQ3[0] + sm.t3.sWQ3[1] + sm.t3.sWQ3[2] + sm.t3.sWQ3[3];
            int slot = tile & (NSLOT - 1);
            atomicAdd(&a.sSum[3 * NSLOT * 32 + slot * 32], S);
            atomicAdd(&a.sSq[3 * NSLOT * 32 + slot * 32], Q);
        }
    }
}

__device__ __forceinline__ void ph10_pool(const KArgs& a, SmU& sm, int bid, int nb, int t) {
    __syncthreads();
    if (t < 97) {
        int layer = (t == 96) ? 3 : (t >> 5);
        int ch = t & 31;
        const float* bg = (layer == 0) ? a.bg0 : (layer == 1) ? a.bg1 : (layer == 2) ? a.bg2 : a.bg3;
        const float* bb = (layer == 0) ? a.bb0 : (layer == 1) ? a.bb1 : (layer == 2) ? a.bb2 : a.bb3;
        bn_coef(a.sSum + layer * NSLOT * 32, a.sSq + layer * NSLOT * 32, bg, bb, a.invN, ch,
                &sm.pool.pcA[t], &sm.pool.pcC[t]);
    }
    __syncthreads();
    int lane = t & 31, slot = t >> 5;
    int arr = lane >> 3, sub = lane & 7;
    const unsigned* yb = (arr == 1) ? (const unsigned*)a.y0b
                       : (arr == 2) ? (const unsigned*)a.y1b : (const unsigned*)a.y2b;
    float4 a4 = make_float4(1.f, 1.f, 1.f, 1.f);
    float4 c4 = make_float4(0.f, 0.f, 0.f, 0.f);
    bool aff = (arr > 0);
    if (aff) {
        a4 = ((const float4*)sm.pool.pcA)[(arr - 1) * 8 + sub];
        c4 = ((const float4*)sm.pool.pcC)[(arr - 1) * 8 + sub];
    }
    float aY = sm.pool.pcA[96], cY = sm.pool.pcC[96];
    for (int g = bid; g < a.G; g += nb) {
        __syncthreads();
        int s0 = a.gstart[g], s1 = a.gstart[g + 1];
        float4 acc = make_float4(0.f, 0.f, 0.f, 0.f);
        for (int n = s0 + slot; n < s1; n += 8) {
            float4 v;
            if (arr == 0) {
                v = ((const float4*)a.h)[(size_t)n * 8 + sub];
            } else {
                uint2 u = ((const uint2*)yb)[(size_t)n * 8 + sub];
                v = make_float4(bfLO(u.x), bfHI(u.x), bfLO(u.y), bfHI(u.y));
            }
            if (aff) {
                float vx = fmaf(a4.x, v.x, c4.x); vx = vx > 0.f ? vx : 0.f;
                float vy = fmaf(a4.y, v.y, c4.y); vy = vy > 0.f ? vy : 0.f;
                float vz = fmaf(a4.z, v.z, c4.z); vz = vz > 0.f ? vz : 0.f;
                float vw = fmaf(a4.w, v.w, c4.w); vw = vw > 0.f ? vw : 0.f;
                v = make_float4(vx, vy, vz, vw);
            }
            acc = f4add(acc, v);
        }
        float ys = 0.f;
        for (int n = s0 + t; n < s1; n += 256) {
            float v = fmaf(aY, a.y3[n], cY);
            ys += v > 0.f ? v : 0.f;
        }
#pragma unroll
        for (int off = 1; off < 64; off <<= 1) ys += __shfl_xor(ys, off, 64);
        if ((t & 63) == 0) sm.pool.sY[t >> 6] = ys;
        ((float4*)&sm.pool.sP[slot][lane * 4])[0] = acc;
        __syncthreads();
        float inv = (s1 > s0) ? 1.f / (float)(s1 - s0) : 1.f;
        if (t < 128) {
            float S = 0.f;
#pragma unroll
            for (int s = 0; s < 8; s++) S += sm.pool.sP[s][t];
            sm.pool.hg[t] = S * inv;
        } else if (t == 128) {
            float S = sm.pool.sY[0] + sm.pool.sY[1] + sm.pool.sY[2] + sm.pool.sY[3];
            sm.pool.hg[128] = S * inv;
        }
        __syncthreads();
        if (t < 128) {
            float v = a.mb0[t];
            for (int i = 0; i < 129; i++) v += sm.pool.hg[i] * a.mw0[i * 128 + t];
            sm.pool.hid1[t] = v > 0.f ? v : 0.f;
        }
        __syncthreads();
        if (t < 64) {
            float v = a.mb1[t];
            for (int i = 0; i < 128; i++) v += sm.pool.hid1[i] * a.mw1[i * 64 + t];
            sm.pool.hid2[t] = v > 0.f ? v : 0.f;
        }
        __syncthreads();
        if (t < 64) {
            float v = sm.pool.hid2[t] * a.mw2[t];
            for (int off = 32; off > 0; off >>= 1) v += __shfl_down(v, off, 64);
            if (t == 0) a.out[g] = v + a.mb2[0];
        }
    }
}

// ---------------- cooperative mega-kernel ----------------

__global__ __launch_bounds__(256, 4) void k_mega(KArgs a) {
    cg::grid_group grid = cg::this_grid();
    __shared__ SmU sm;
    const int t = threadIdx.x, bid = blockIdx.x, nb = gridDim.x;
    ph1_hist_t0(a, sm, bid, nb, t);  __threadfence(); grid.sync();
    ph2_scanA(a, bid, nb, t);        __threadfence(); grid.sync();
    ph3_scatter(a, sm, bid, t);      __threadfence(); grid.sync();
    ph4_sortb(a, sm, bid, nb, t);    __threadfence(); grid.sync();
    ph5_agg0(a, sm, bid, nb, t);     __threadfence(); grid.sync();
    ph6_aggF1(a, sm, bid, nb, t);    __threadfence(); grid.sync();
    ph7_aggF2(a, sm, bid, nb, t);    __threadfence(); grid.sync();
    ph8_t3(a, sm, bid, nb, t);       __threadfence(); grid.sync();
    ph9_agg3(a, sm, bid, nb, t);     __threadfence(); grid.sync();
    ph10_pool(a, sm, bid, nb, t);
}

// ---------------- fallback wrappers (multi-kernel pipeline) ----------------

__global__ __launch_bounds__(256) void k_p1(KArgs a)
{ __shared__ SmU sm; ph1_hist_t0(a, sm, blockIdx.x, gridDim.x, threadIdx.x); }
__global__ __launch_bounds__(256) void k_p2(KArgs a)
{ ph2_scanA(a, blockIdx.x, gridDim.x, threadIdx.x); }
__global__ __launch_bounds__(256) void k_p3(KArgs a)
{ __shared__ SmU sm; ph3_scatter(a, sm, blockIdx.x, threadIdx.x); }
__global__ __launch_bounds__(256) void k_p4(KArgs a)
{ __shared__ SmU sm; ph4_sortb(a, sm, blockIdx.x, gridDim.x, threadIdx.x); }
__global__ __launch_bounds__(256, 6) void k_p5(KArgs a)
{ __shared__ SmU sm; ph5_agg0(a, sm, blockIdx.x, gridDim.x, threadIdx.x); }
__global__ __launch_bounds__(256, 4) void k_p6(KArgs a)
{ __shared__ SmU sm; ph6_aggF1(a, sm, blockIdx.x, gridDim.x, threadIdx.x); }
__global__ __launch_bounds__(256, 4) void k_p7(KArgs a)
{ __shared__ SmU sm; ph7_aggF2(a, sm, blockIdx.x, gridDim.x, threadIdx.x); }
__global__ __launch_bounds__(256) void k_p8(KArgs a)
{ __shared__ SmU sm; ph8_t3(a, sm, blockIdx.x, gridDim.x, threadIdx.x); }
__global__ __launch_bounds__(256) void k_p9(KArgs a)
{ __shared__ SmU sm; ph9_agg3(a, sm, blockIdx.x, gridDim.x, threadIdx.x); }
__global__ __launch_bounds__(256) void k_p10(KArgs a)
{ __shared__ SmU sm; ph10_pool(a, sm, blockIdx.x, gridDim.x, threadIdx.x); }

// ---------------- launcher ----------------

extern "C" void kernel_launch(void* const* d_in, const int* in_sizes, int n_in,
                              void* d_out, int out_size, void* d_ws, size_t ws_size,
                              hipStream_t stream) {
    KArgs ka;
    ka.h   = (const float*)d_in[0];
    ka.src = (const int*)d_in[1];
    ka.dst = (const int*)d_in[2];
    ka.gid = (const int*)d_in[3];
    const float* convw[4], *convb[4], *bng[4], *bnb[4];
    for (int i = 0; i < 4; i++) {
        convw[i] = (const float*)d_in[4 + 4 * i];
        convb[i] = (const float*)d_in[5 + 4 * i];
        bng[i]   = (const float*)d_in[6 + 4 * i];
        bnb[i]   = (const float*)d_in[7 + 4 * i];
    }
    ka.W0 = convw[0]; ka.b0c = convb[0]; ka.W1 = convw[1]; ka.b1c = convb[1];
    ka.W2 = convw[2]; ka.b2c = convb[2]; ka.w3 = convw[3]; ka.b3c = convb[3];
    ka.bg0 = bng[0]; ka.bb0 = bnb[0]; ka.bg1 = bng[1]; ka.bb1 = bnb[1];
    ka.bg2 = bng[2]; ka.bb2 = bnb[2]; ka.bg3 = bng[3]; ka.bb3 = bnb[3];
    ka.mw0 = (const float*)d_in[20]; ka.mb0 = (const float*)d_in[21];
    ka.mw1 = (const float*)d_in[22]; ka.mb1 = (const float*)d_in[23];
    ka.mw2 = (const float*)d_in[24]; ka.mb2 = (const float*)d_in[25];

    const int N = in_sizes[0] / 32;
    const int E = in_sizes[1];
    const int G = out_size;
    const int nbuck = cdiv_h(N, BKN);
    const int chunk = cdiv_h(E, NSB);

    char* ws = (char*)d_ws;
    size_t off = 0;
    auto alloc = [&](size_t bytes) -> void* {
        void* p = ws + off;
        off += (bytes + 511) & ~(size_t)511;
        return p;
    };
    ka.histT   = (int*)alloc((size_t)NSB * nbuck * 4);
    ka.prefixB = (int*)alloc((size_t)nbuck * NSB * 4);
    ka.totalP  = (int*)alloc((size_t)nbuck * 4);
    ka.totalU  = (int*)alloc((size_t)nbuck * 4);
    size_t ebufE = (size_t)E + (size_t)16 * NSB * nbuck;
    ka.ebuf = (unsigned*)alloc(ebufE * 4);
    ka.pb   = (uint4*)alloc((size_t)N * 64);     // reused as fp32 q in ph8/ph9
    ka.col  = (int*)alloc((size_t)E * 4);
    ka.rs   = (int*)alloc((size_t)N * 4);
    ka.re   = (int*)alloc((size_t)N * 4);
    ka.gstart = (int*)alloc((size_t)(G + 1) * 4);
    ka.y0b  = (uint4*)alloc((size_t)N * 64);
    ka.y1b  = (uint4*)alloc((size_t)N * 64);
    ka.y2b  = (uint4*)alloc((size_t)N * 64);
    ka.y3   = (float*)alloc((size_t)N * 4);
    ka.sSum = (float*)alloc((size_t)4 * NSLOT * 32 * 4);
    ka.sSq  = (float*)alloc((size_t)4 * NSLOT * 32 * 4);
    ka.out  = (float*)d_out;
    (void)ws_size; (void)n_in;

    ka.N = N; ka.E = E; ka.G = G; ka.nbuck = nbuck; ka.chunk = chunk;
    ka.NT64 = cdiv_h(N, 64); ka.NT256 = cdiv_h(N, 256);
    ka.invN = 1.f / (float)N;

    void* params[] = { (void*)&ka };
    static const int ladder[4] = { 1024, 768, 512, 384 };   // all > NSB so ph1's t0 blocks exist
    hipError_t e = hipErrorUnknown;
    for (int i = 0; i < 4 && e != hipSuccess; i++) {
        e = hipLaunchCooperativeKernel((const void*)k_mega, dim3(ladder[i]), dim3(256), params, 0, stream);
        if (e != hipSuccess) (void)hipGetLastError();   // clear sticky error before retry/fallback
    }
    if (e != hipSuccess) {
        // fallback: known-good 10-dispatch pipeline
        k_p1<<<NSB + ka.NT256, 256, 0, stream>>>(ka);
        k_p2<<<nbuck, 256, 0, stream>>>(ka);
        k_p3<<<NSB, 256, 0, stream>>>(ka);
        k_p4<<<nbuck, 256, 0, stream>>>(ka);
        k_p5<<<ka.NT64, 256, 0, stream>>>(ka);
        k_p6<<<ka.NT64, 256, 0, stream>>>(ka);
        k_p7<<<ka.NT64, 256, 0, stream>>>(ka);
        k_p8<<<ka.NT256, 256, 0, stream>>>(ka);
        k_p9<<<ka.NT256, 256, 0, stream>>>(ka);
        k_p10<<<G, 256, 0, stream>>>(ka);
    }
}

// Round 8
// 294.566 us; speedup vs baseline: 7.7413x; 7.6132x over previous
//
#include <hip/hip_runtime.h>

#define NSLOT 32
#define BN_EPS 1e-5f
#define NSB 256             // hist/scatter slices
#define BKBITS 8
#define BKN 256             // nodes per bucket
#define MAXBUCK 512

static inline int cdiv_h(int a, int b) { return (a + b - 1) / b; }

__device__ __forceinline__ float4 f4add(float4 a, float4 b) {
    return make_float4(a.x + b.x, a.y + b.y, a.z + b.z, a.w + b.w);
}

__device__ __forceinline__ unsigned bf16rtn(float x) {
    unsigned u = __float_as_uint(x);
    return (u + 0x7FFFu + ((u >> 16) & 1u)) >> 16;
}
__device__ __forceinline__ unsigned bf16pack2(float lo, float hi) {
    return bf16rtn(lo) | (bf16rtn(hi) << 16);
}
__device__ __forceinline__ float bfLO(unsigned u) { return __uint_as_float(u << 16); }
__device__ __forceinline__ float bfHI(unsigned u) { return __uint_as_float(u & 0xFFFF0000u); }

__device__ __forceinline__ int blk_excl_scan256(int v, int t) {
    __shared__ int wsum[4];
    int l = t & 63, w = t >> 6;
    int incl = v;
#pragma unroll
    for (int off = 1; off < 64; off <<= 1) {
        int o = __shfl_up(incl, off, 64);
        if (l >= off) incl += o;
    }
    if (l == 63) wsum[w] = incl;
    __syncthreads();
    int wofs = 0;
#pragma unroll
    for (int i = 0; i < 4; i++) wofs += (i < w) ? wsum[i] : 0;
    __syncthreads();
    return wofs + incl - v;
}

__device__ __forceinline__ void bn_coef(const float* __restrict__ sSum, const float* __restrict__ sSq,
                                        const float* __restrict__ bg, const float* __restrict__ bb,
                                        float invN, int ch, float* aOut, float* cOut) {
    float S = 0.f, Q = 0.f;
#pragma unroll
    for (int s = 0; s < NSLOT; s++) { S += sSum[s * 32 + ch]; Q += sSq[s * 32 + ch]; }
    float m = S * invN;
    float var = Q * invN - m * m;
    if (var < 0.f) var = 0.f;
    float iv = rsqrtf(var + BN_EPS);
    float a = bg[ch] * iv;
    *aOut = a;
    *cOut = bb[ch] - m * a;
}

__device__ __forceinline__ void inline_scan512(const int* __restrict__ tot, int* __restrict__ sOut,
                                               int* __restrict__ sTot, int nbuck, int t) {
    int v0 = (t < nbuck) ? tot[t] : 0;
    int v1 = (256 + t < nbuck) ? tot[256 + t] : 0;
    int e0 = blk_excl_scan256(v0, t);
    if (t == 255) *sTot = e0 + v0;
    __syncthreads();
    int e1 = blk_excl_scan256(v1, t) + *sTot;
    sOut[t] = e0;
    sOut[256 + t] = e1;
    __syncthreads();
}

__device__ __forceinline__ void accPlain(float* dst, uint4 v) {
    dst[0] += bfLO(v.x); dst[1] += bfHI(v.x);
    dst[2] += bfLO(v.y); dst[3] += bfHI(v.y);
    dst[4] += bfLO(v.z); dst[5] += bfHI(v.z);
    dst[6] += bfLO(v.w); dst[7] += bfHI(v.w);
}
__device__ __forceinline__ void accAff(float* dst, uint4 v, const float* a8, const float* c8) {
    float x[8] = { bfLO(v.x), bfHI(v.x), bfLO(v.y), bfHI(v.y),
                   bfLO(v.z), bfHI(v.z), bfLO(v.w), bfHI(v.w) };
#pragma unroll
    for (int q = 0; q < 8; q++) { float r = fmaf(a8[q], x[q], c8[q]); dst[q] += r > 0.f ? r : 0.f; }
}

struct KArgs {
    const float* h; const int* src; const int* dst; const int* gid;
    const float* W0; const float* b0c; const float* W1; const float* b1c;
    const float* W2; const float* b2c; const float* w3; const float* b3c;
    const float* bg0; const float* bb0; const float* bg1; const float* bb1;
    const float* bg2; const float* bb2; const float* bg3; const float* bb3;
    const float* mw0; const float* mb0; const float* mw1; const float* mb1;
    const float* mw2; const float* mb2;
    int* histT; int* prefixB; int* totalP; int* totalU;
    unsigned* ebuf; uint4* hb; int* col; int* rs; int* re; int* gstart;
    uint4* y0b; uint4* y1b; uint4* y2b; float* y3;
    float* sSum; float* sSq; float* out;
    int N, E, G, nbuck, chunk, NT64, NT256;
    float invN;
};

// ---------------- p1: hist slices (bid<NSB) | bf16-pack of h (bid>=NSB); zero stats ------------

__global__ __launch_bounds__(256) void k_p1(KArgs a) {
    __shared__ int bins[MAXBUCK];
    int t = threadIdx.x, bid = blockIdx.x;
    if (bid < NSB) {
        if (bid == 0) {
            for (int i = t; i < 4 * NSLOT * 32; i += 256) { a.sSum[i] = 0.f; a.sSq[i] = 0.f; }
        }
        for (int b = t; b < a.nbuck; b += 256) bins[b] = 0;
        __syncthreads();
        int lo = bid * a.chunk, hi = lo + a.chunk; if (hi > a.E) hi = a.E;
        for (int i = lo + t; i < hi; i += 256) atomicAdd(&bins[a.dst[i] >> BKBITS], 1);
        __syncthreads();
        for (int b = t; b < a.nbuck; b += 256) a.histT[bid * a.nbuck + b] = bins[b];
    } else {
        // pack h (fp32 x32) -> hb (bf16 x32, 64B/node). Layer-0 matmul moved post-mean (p5).
        int node = (bid - NSB) * 256 + t;
        if (node < a.N) {
            const float4* s4 = (const float4*)a.h + (size_t)node * 8;
            float x[32];
#pragma unroll
            for (int q = 0; q < 8; q++) {
                float4 v = s4[q];
                x[4*q] = v.x; x[4*q+1] = v.y; x[4*q+2] = v.z; x[4*q+3] = v.w;
            }
            uint4* d4 = a.hb + (size_t)node * 4;
#pragma unroll
            for (int q = 0; q < 4; q++) {
                uint4 o;
                o.x = bf16pack2(x[8*q+0], x[8*q+1]);
                o.y = bf16pack2(x[8*q+2], x[8*q+3]);
                o.z = bf16pack2(x[8*q+4], x[8*q+5]);
                o.w = bf16pack2(x[8*q+6], x[8*q+7]);
                d4[q] = o;
            }
        }
    }
}

// ---------------- p2: per-bucket cell scan + gstart ----------------

__global__ __launch_bounds__(256) void k_p2(KArgs a) {
    int b = blockIdx.x, t = threadIdx.x;
    int i = b * 256 + t;
    if (i < a.N) {
        int g = a.gid[i];
        int gp = (i == 0) ? -1 : a.gid[i - 1];
        for (int x = gp + 1; x <= g; ++x) a.gstart[x] = i;
        if (i == a.N - 1) { for (int x = g + 1; x <= a.G; ++x) a.gstart[x] = a.N; }
    }
    int c = a.histT[t * a.nbuck + b];
    int pad = (c + 15) & ~15;
    int ep = blk_excl_scan256(pad, t);
    a.prefixB[b * NSB + t] = ep;
    int ec = blk_excl_scan256(c, t);
    if (t == NSB - 1) { a.totalP[b] = ep + pad; a.totalU[b] = ec + c; }
}

// ---------------- p3: deterministic scatter (LDS cursors, inline cross-bucket scan) ------------

__global__ __launch_bounds__(256) void k_p3(KArgs a) {
    __shared__ int sBP[512];
    __shared__ int sTot;
    __shared__ int cur[MAXBUCK];
    int bid = blockIdx.x, t = threadIdx.x;
    inline_scan512(a.totalP, sBP, &sTot, a.nbuck, t);
    for (int b = t; b < a.nbuck; b += 256) cur[b] = sBP[b] + a.prefixB[b * NSB + bid];
    __syncthreads();
    int lo = bid * a.chunk, hi = lo + a.chunk; if (hi > a.E) hi = a.E;
    for (int i = lo + t; i < hi; i += 256) {
        int d = a.dst[i], s = a.src[i];
        int b = d >> BKBITS;
        int pos = atomicAdd(&cur[b], 1);
        a.ebuf[pos] = ((unsigned)(d & (BKN - 1)) << 24) | (unsigned)s;
    }
}

// ---------------- p4: per-bucket counting sort -> col/rs/re ----------------

__global__ __launch_bounds__(256) void k_p4(KArgs a) {
    __shared__ int sBP[512];
    __shared__ int sTot;
    __shared__ int binCnt[BKN], binStart[BKN], cursor[BKN];
    __shared__ int cellBase[NSB], cellCnt[NSB];
    int b = blockIdx.x, t = threadIdx.x;
    inline_scan512(a.totalP, sBP, &sTot, a.nbuck, t);
    int basePb = sBP[b];
    __syncthreads();
    inline_scan512(a.totalU, sBP, &sTot, a.nbuck, t);
    int baseUb = sBP[b];
    cellBase[t] = basePb + a.prefixB[b * NSB + t];
    cellCnt[t]  = a.histT[t * a.nbuck + b];
    binCnt[t] = 0; cursor[t] = 0;
    __syncthreads();
    {
        int cb = cellBase[t], cc = cellCnt[t];
        for (int j = 0; j < cc; j++) atomicAdd(&binCnt[a.ebuf[cb + j] >> 24], 1);
    }
    __syncthreads();
    int bs = blk_excl_scan256(binCnt[t], t);
    binStart[t] = bs;
    __syncthreads();
    {
        int cb = cellBase[t], cc = cellCnt[t];
        for (int j = 0; j < cc; j++) {
            unsigned e = a.ebuf[cb + j];
            int l = e >> 24;
            int pos = binStart[l] + atomicAdd(&cursor[l], 1);
            a.col[baseUb + pos] = (int)(e & 0xFFFFFFu);
        }
    }
    int node = b * BKN + t;
    if (node < a.N) {
        a.rs[node] = baseUb + binStart[t];
        a.re[node] = baseUb + binStart[t] + binCnt[t];
    }
}

// ---------------- gather+mean tile with @W epilogue ----------------
// AFF=false (layer 0): plain bf16 accumulate, mean, @W + bias -> y out.
// AFF=true  (layers 1/2): per-edge affine+relu (folded prev BN), mean, @W + bias -> y out.
// Shared LDS layout (caller owns): scol[2112] | sW[32][32] | sWS/sWQ[4][32]

template <bool AFF>
__device__ __forceinline__ void agg_tile(const KArgs& a, int* scol, float (*sW)[32],
                                         float (*sWS)[32], float (*sWQ)[32], int tile, int t,
                                         const uint4* __restrict__ yin, uint4* __restrict__ yout,
                                         const float* __restrict__ bias, const float* a8, const float* c8,
                                         float* __restrict__ oSum, float* __restrict__ oSq) {
    int lane = t & 3, grp = t >> 2;
    int node0 = tile * 64, node = node0 + grp;
    int base0 = 0, len = 0;
    if (node0 < a.N) {
        int last = node0 + 63; if (last > a.N - 1) last = a.N - 1;
        base0 = a.rs[node0];
        len = a.re[last] - base0;
    }
    bool lds = (len > 0 && len <= 2048);
    if (lds) { for (int i = t; i < len; i += 256) scol[i] = a.col[base0 + i]; }
    __syncthreads();

    float accA[8], accB[8];
#pragma unroll
    for (int q = 0; q < 8; q++) { accA[q] = 0.f; accB[q] = 0.f; }
    float vout[8];
#pragma unroll
    for (int q = 0; q < 8; q++) vout[q] = 0.f;
    int s0 = 0, s1 = 0;
    if (node < a.N) {
        s0 = a.rs[node]; s1 = a.re[node];
#define GATH2(vv, c) vv = yin[(size_t)(c) * 4 + lane]
#define DOACC(d, g) do { if (AFF) accAff(d, g, a8, c8); else accPlain(d, g); } while (0)
        const int* idx = lds ? scol : a.col;
        int j = lds ? s0 - base0 : s0;
        int j1 = lds ? s1 - base0 : s1;
        if (j + 4 <= j1) {
            uint4 g0, g1, g2, g3;
            GATH2(g0, idx[j]); GATH2(g1, idx[j + 1]); GATH2(g2, idx[j + 2]); GATH2(g3, idx[j + 3]);
            j += 4;
            for (; j + 4 <= j1; j += 4) {
                uint4 h0, h1, h2, h3;
                GATH2(h0, idx[j]); GATH2(h1, idx[j + 1]); GATH2(h2, idx[j + 2]); GATH2(h3, idx[j + 3]);
                DOACC(accA, g0); DOACC(accB, g1); DOACC(accA, g2); DOACC(accB, g3);
                g0 = h0; g1 = h1; g2 = h2; g3 = h3;
            }
            DOACC(accA, g0); DOACC(accB, g1); DOACC(accA, g2); DOACC(accB, g3);
        }
        for (; j < j1; ++j) { uint4 g; GATH2(g, idx[j]); DOACC(accA, g); }
#undef GATH2
#undef DOACC
    }
    // mean -> LDS (scol overlay; all gathers done), then @W epilogue
    float* sM = (float*)scol;
    __syncthreads();
    if (node < a.N) {
        int deg = s1 - s0;
        float inv = (deg > 0) ? 1.f / (float)deg : 1.f;
#pragma unroll
        for (int q = 0; q < 8; q++) sM[grp * 33 + lane * 8 + q] = (accA[q] + accB[q]) * inv;
    }
    __syncthreads();
    if (node < a.N) {
        const float4* b4 = (const float4*)bias;
        float4 b0 = b4[lane * 2], b1 = b4[lane * 2 + 1];
        float outv[8] = { b0.x, b0.y, b0.z, b0.w, b1.x, b1.y, b1.z, b1.w };
#pragma unroll
        for (int k = 0; k < 32; k++) {
            float mk = sM[grp * 33 + k];
#pragma unroll
            for (int q = 0; q < 8; q++) outv[q] += mk * sW[k][lane * 8 + q];
        }
#pragma unroll
        for (int q = 0; q < 8; q++) vout[q] = outv[q];
        uint4 o;
        o.x = bf16pack2(vout[0], vout[1]);
        o.y = bf16pack2(vout[2], vout[3]);
        o.z = bf16pack2(vout[4], vout[5]);
        o.w = bf16pack2(vout[6], vout[7]);
        yout[(size_t)node * 4 + lane] = o;
    }
    // BN stats: wave shfl_xor across the 16 groups, cross-wave LDS combine, one atomic per ch
    float sqv[8];
#pragma unroll
    for (int q = 0; q < 8; q++) sqv[q] = vout[q] * vout[q];
#pragma unroll
    for (int off = 4; off < 64; off <<= 1) {
#pragma unroll
        for (int q = 0; q < 8; q++) {
            vout[q] += __shfl_xor(vout[q], off, 64);
            sqv[q]  += __shfl_xor(sqv[q],  off, 64);
        }
    }
    int w = t >> 6, l = t & 63;
    if (l < 4) {
#pragma unroll
        for (int q = 0; q < 8; q++) { sWS[w][l * 8 + q] = vout[q]; sWQ[w][l * 8 + q] = sqv[q]; }
    }
    __syncthreads();
    if (t < 32) {
        float S = sWS[0][t] + sWS[1][t] + sWS[2][t] + sWS[3][t];
        float Q = sWQ[0][t] + sWQ[1][t] + sWQ[2][t] + sWQ[3][t];
        int slot = tile & (NSLOT - 1);
        atomicAdd(&oSum[slot * 32 + t], S);
        atomicAdd(&oSq[slot * 32 + t], Q);
    }
}

// ---------------- p5: layer 0 = (mean hb) @ W0 + b0 ----------------

__global__ __launch_bounds__(256, 4) void k_p5(KArgs a) {
    __shared__ int scol[2112];
    __shared__ float sW[32][32];
    __shared__ float sWS[4][32];
    __shared__ float sWQ[4][32];
    int t = threadIdx.x;
    for (int i = t; i < 1024; i += 256) sW[i >> 5][i & 31] = a.W0[i];
    __syncthreads();
    agg_tile<false>(a, scol, sW, sWS, sWQ, blockIdx.x, t, a.hb, a.y0b, a.b0c, nullptr, nullptr,
                    a.sSum + 0 * NSLOT * 32, a.sSq + 0 * NSLOT * 32);
}

// ---------------- p6/p7: fused layers 1/2 ----------------

__device__ __forceinline__ void aggF_kernel(const KArgs& a, const uint4* yin, uint4* yout,
                                            const float* W, const float* bias,
                                            const float* pSum, const float* pSq,
                                            const float* bg, const float* bb,
                                            float* oSum, float* oSq) {
    __shared__ int scol[2112];
    __shared__ float sW[32][32];
    __shared__ float sA[32], sC[32];
    __shared__ float sWS[4][32];
    __shared__ float sWQ[4][32];
    int t = threadIdx.x;
    for (int i = t; i < 1024; i += 256) sW[i >> 5][i & 31] = W[i];
    if (t < 32) bn_coef(pSum, pSq, bg, bb, a.invN, t, &sA[t], &sC[t]);
    __syncthreads();
    float a8[8], c8[8];
    int lane = t & 3;
#pragma unroll
    for (int q = 0; q < 8; q++) { a8[q] = sA[lane * 8 + q]; c8[q] = sC[lane * 8 + q]; }
    agg_tile<true>(a, scol, sW, sWS, sWQ, blockIdx.x, t, yin, yout, bias, a8, c8, oSum, oSq);
}

__global__ __launch_bounds__(256, 4) void k_p6(KArgs a) {
    aggF_kernel(a, a.y0b, a.y1b, a.W1, a.b1c,
                a.sSum + 0 * NSLOT * 32, a.sSq + 0 * NSLOT * 32, a.bg0, a.bb0,
                a.sSum + 1 * NSLOT * 32, a.sSq + 1 * NSLOT * 32);
}
__global__ __launch_bounds__(256, 4) void k_p7(KArgs a) {
    aggF_kernel(a, a.y1b, a.y2b, a.W2, a.b2c,
                a.sSum + 1 * NSLOT * 32, a.sSq + 1 * NSLOT * 32, a.bg1, a.bb1,
                a.sSum + 2 * NSLOT * 32, a.sSq + 2 * NSLOT * 32);
}

// ---------------- p8: transform3 q[v] = relu(a*y2+c) . w3 (scalar per node) ----------------

__global__ __launch_bounds__(256) void k_p8(KArgs a) {
    __shared__ float sw[32], sA[32], sC[32];
    int t = threadIdx.x;
    float* q = (float*)a.hb;         // hb dead after p5
    if (t < 32) {
        sw[t] = a.w3[t];
        bn_coef(a.sSum + 2 * NSLOT * 32, a.sSq + 2 * NSLOT * 32, a.bg2, a.bb2,
                a.invN, t, &sA[t], &sC[t]);
    }
    __syncthreads();
    int i = blockIdx.x * 256 + t;
    if (i < a.N) {
        const uint4* x4 = a.y2b + (size_t)i * 4;
        float acc = 0.f;
#pragma unroll
        for (int qq = 0; qq < 4; qq++) {
            uint4 u = x4[qq];
            float vv[8] = { bfLO(u.x), bfHI(u.x), bfLO(u.y), bfHI(u.y),
                            bfLO(u.z), bfHI(u.z), bfLO(u.w), bfHI(u.w) };
#pragma unroll
            for (int r = 0; r < 8; r++) {
                int k = qq * 8 + r;
                float xv = sA[k] * vv[r] + sC[k];
                xv = xv > 0.f ? xv : 0.f;
                acc += xv * sw[k];
            }
        }
        q[i] = acc;
    }
}

// ---------------- p9: aggregate3 (4B scalar gather) + BN3 stats ----------------

__global__ __launch_bounds__(256) void k_p9(KArgs a) {
    __shared__ float sWS3[4], sWQ3[4];
    const float* q = (const float*)a.hb;
    int t = threadIdx.x;
    int i = blockIdx.x * 256 + t;
    float lsum = 0.f, lsq = 0.f;
    if (i < a.N) {
        int s0 = a.rs[i], s1 = a.re[i];
        float a0 = 0.f, a1 = 0.f, a2 = 0.f, a3 = 0.f;
        int j = s0;
        if (j + 4 <= s1) {
            float g0 = q[a.col[j]], g1 = q[a.col[j+1]], g2 = q[a.col[j+2]], g3 = q[a.col[j+3]];
            j += 4;
            for (; j + 4 <= s1; j += 4) {
                float h0 = q[a.col[j]], h1 = q[a.col[j+1]], h2 = q[a.col[j+2]], h3 = q[a.col[j+3]];
                a0 += g0; a1 += g1; a2 += g2; a3 += g3;
                g0 = h0; g1 = h1; g2 = h2; g3 = h3;
            }
            a0 += g0; a1 += g1; a2 += g2; a3 += g3;
        }
        for (; j < s1; ++j) a0 += q[a.col[j]];
        float acc = (a0 + a1) + (a2 + a3);
        float inv = (s1 > s0) ? 1.f / (float)(s1 - s0) : 1.f;
        float v = acc * inv + a.b3c[0];
        a.y3[i] = v; lsum = v; lsq = v * v;
    }
#pragma unroll
    for (int off = 1; off < 64; off <<= 1) {
        lsum += __shfl_xor(lsum, off, 64);
        lsq  += __shfl_xor(lsq,  off, 64);
    }
    if ((t & 63) == 0) { sWS3[t >> 6] = lsum; sWQ3[t >> 6] = lsq; }
    __syncthreads();
    if (t == 0) {
        float S = sWS3[0] + sWS3[1] + sWS3[2] + sWS3[3];
        float Q = sWQ3[0] + sWQ3[1] + sWQ3[2] + sWQ3[3];
        int slot = blockIdx.x & (NSLOT - 1);
        atomicAdd(&a.sSum[3 * NSLOT * 32 + slot * 32], S);
        atomicAdd(&a.sSq[3 * NSLOT * 32 + slot * 32], Q);
    }
}

// ---------------- p10: per-graph mean pool + MLP ----------------

__global__ __launch_bounds__(256) void k_p10(KArgs a) {
    __shared__ float pcA[128], pcC[128];
    __shared__ float sP[8][128];
    __shared__ float sY[4];
    __shared__ float hg[129];
    __shared__ float hid1[128];
    __shared__ float hid2[64];
    int g = blockIdx.x;
    int t = threadIdx.x;
    if (t < 97) {
        int layer = (t == 96) ? 3 : (t >> 5);
        int ch = t & 31;
        const float* bg = (layer == 0) ? a.bg0 : (layer == 1) ? a.bg1 : (layer == 2) ? a.bg2 : a.bg3;
        const float* bb = (layer == 0) ? a.bb0 : (layer == 1) ? a.bb1 : (layer == 2) ? a.bb2 : a.bb3;
        bn_coef(a.sSum + layer * NSLOT * 32, a.sSq + layer * NSLOT * 32, bg, bb, a.invN, ch,
                &pcA[t], &pcC[t]);
    }
    __syncthreads();
    int s0 = a.gstart[g], s1 = a.gstart[g + 1];
    int lane = t & 31, slot = t >> 5;
    int arr = lane >> 3, sub = lane & 7;
    const unsigned* yb = (arr == 1) ? (const unsigned*)a.y0b
                       : (arr == 2) ? (const unsigned*)a.y1b : (const unsigned*)a.y2b;
    float4 a4 = make_float4(1.f, 1.f, 1.f, 1.f);
    float4 c4 = make_float4(0.f, 0.f, 0.f, 0.f);
    bool aff = (arr > 0);
    if (aff) {
        a4 = ((const float4*)pcA)[(arr - 1) * 8 + sub];
        c4 = ((const float4*)pcC)[(arr - 1) * 8 + sub];
    }
    float4 acc = make_float4(0.f, 0.f, 0.f, 0.f);
    for (int n = s0 + slot; n < s1; n += 8) {
        float4 v;
        if (arr == 0) {
            v = ((const float4*)a.h)[(size_t)n * 8 + sub];
        } else {
            uint2 u = ((const uint2*)yb)[(size_t)n * 8 + sub];
            v = make_float4(bfLO(u.x), bfHI(u.x), bfLO(u.y), bfHI(u.y));
        }
        if (aff) {
            float vx = fmaf(a4.x, v.x, c4.x); vx = vx > 0.f ? vx : 0.f;
            float vy = fmaf(a4.y, v.y, c4.y); vy = vy > 0.f ? vy : 0.f;
            float vz = fmaf(a4.z, v.z, c4.z); vz = vz > 0.f ? vz : 0.f;
            float vw = fmaf(a4.w, v.w, c4.w); vw = vw > 0.f ? vw : 0.f;
            v = make_float4(vx, vy, vz, vw);
        }
        acc = f4add(acc, v);
    }
    float ys = 0.f;
    {
        float aY = pcA[96], cY = pcC[96];
        for (int n = s0 + t; n < s1; n += 256) {
            float v = fmaf(aY, a.y3[n], cY);
            ys += v > 0.f ? v : 0.f;
        }
    }
#pragma unroll
    for (int off = 1; off < 64; off <<= 1) ys += __shfl_xor(ys, off, 64);
    if ((t & 63) == 0) sY[t >> 6] = ys;
    ((float4*)&sP[slot][lane * 4])[0] = acc;
    __syncthreads();
    float inv = (s1 > s0) ? 1.f / (float)(s1 - s0) : 1.f;
    if (t < 128) {
        float S = 0.f;
#pragma unroll
        for (int s = 0; s < 8; s++) S += sP[s][t];
        hg[t] = S * inv;
    } else if (t == 128) {
        float S = sY[0] + sY[1] + sY[2] + sY[3];
        hg[128] = S * inv;
    }
    __syncthreads();
    if (t < 128) {
        float v = a.mb0[t];
        for (int i = 0; i < 129; i++) v += hg[i] * a.mw0[i * 128 + t];
        hid1[t] = v > 0.f ? v : 0.f;
    }
    __syncthreads();
    if (t < 64) {
        float v = a.mb1[t];
        for (int i = 0; i < 128; i++) v += hid1[i] * a.mw1[i * 64 + t];
        hid2[t] = v > 0.f ? v : 0.f;
    }
    __syncthreads();
    if (t < 64) {
        float v = hid2[t] * a.mw2[t];
        for (int off = 32; off > 0; off >>= 1) v += __shfl_down(v, off, 64);
        if (t == 0) a.out[g] = v + a.mb2[0];
    }
}

// ---------------- launcher (9 dispatches) ----------------

extern "C" void kernel_launch(void* const* d_in, const int* in_sizes, int n_in,
                              void* d_out, int out_size, void* d_ws, size_t ws_size,
                              hipStream_t stream) {
    KArgs ka;
    ka.h   = (const float*)d_in[0];
    ka.src = (const int*)d_in[1];
    ka.dst = (const int*)d_in[2];
    ka.gid = (const int*)d_in[3];
    const float* convw[4], *convb[4], *bng[4], *bnb[4];
    for (int i = 0; i < 4; i++) {
        convw[i] = (const float*)d_in[4 + 4 * i];
        convb[i] = (const float*)d_in[5 + 4 * i];
        bng[i]   = (const float*)d_in[6 + 4 * i];
        bnb[i]   = (const float*)d_in[7 + 4 * i];
    }
    ka.W0 = convw[0]; ka.b0c = convb[0]; ka.W1 = convw[1]; ka.b1c = convb[1];
    ka.W2 = convw[2]; ka.b2c = convb[2]; ka.w3 = convw[3]; ka.b3c = convb[3];
    ka.bg0 = bng[0]; ka.bb0 = bnb[0]; ka.bg1 = bng[1]; ka.bb1 = bnb[1];
    ka.bg2 = bng[2]; ka.bb2 = bnb[2]; ka.bg3 = bng[3]; ka.bb3 = bnb[3];
    ka.mw0 = (const float*)d_in[20]; ka.mb0 = (const float*)d_in[21];
    ka.mw1 = (const float*)d_in[22]; ka.mb1 = (const float*)d_in[23];
    ka.mw2 = (const float*)d_in[24]; ka.mb2 = (const float*)d_in[25];

    const int N = in_sizes[0] / 32;
    const int E = in_sizes[1];
    const int G = out_size;
    const int nbuck = cdiv_h(N, BKN);
    const int chunk = cdiv_h(E, NSB);

    char* ws = (char*)d_ws;
    size_t off = 0;
    auto alloc = [&](size_t bytes) -> void* {
        void* p = ws + off;
        off += (bytes + 511) & ~(size_t)511;
        return p;
    };
    ka.histT   = (int*)alloc((size_t)NSB * nbuck * 4);
    ka.prefixB = (int*)alloc((size_t)nbuck * NSB * 4);
    ka.totalP  = (int*)alloc((size_t)nbuck * 4);
    ka.totalU  = (int*)alloc((size_t)nbuck * 4);
    size_t ebufE = (size_t)E + (size_t)16 * NSB * nbuck;
    ka.ebuf = (unsigned*)alloc(ebufE * 4);
    ka.hb   = (uint4*)alloc((size_t)N * 64);     // bf16 h; reused as fp32 q in p8/p9
    ka.col  = (int*)alloc((size_t)E * 4);
    ka.rs   = (int*)alloc((size_t)N * 4);
    ka.re   = (int*)alloc((size_t)N * 4);
    ka.gstart = (int*)alloc((size_t)(G + 1) * 4);
    ka.y0b  = (uint4*)alloc((size_t)N * 64);
    ka.y1b  = (uint4*)alloc((size_t)N * 64);
    ka.y2b  = (uint4*)alloc((size_t)N * 64);
    ka.y3   = (float*)alloc((size_t)N * 4);
    ka.sSum = (float*)alloc((size_t)4 * NSLOT * 32 * 4);
    ka.sSq  = (float*)alloc((size_t)4 * NSLOT * 32 * 4);
    ka.out  = (float*)d_out;
    (void)ws_size; (void)n_in;

    ka.N = N; ka.E = E; ka.G = G; ka.nbuck = nbuck; ka.chunk = chunk;
    ka.NT64 = cdiv_h(N, 64); ka.NT256 = cdiv_h(N, 256);
    ka.invN = 1.f / (float)N;

    k_p1<<<NSB + ka.NT256, 256, 0, stream>>>(ka);   // hist + h->bf16 pack
    k_p2<<<nbuck, 256, 0, stream>>>(ka);            // cell scan + gstart
    k_p3<<<NSB, 256, 0, stream>>>(ka);              // deterministic scatter
    k_p4<<<nbuck, 256, 0, stream>>>(ka);            // counting sort -> col/rs/re
    k_p5<<<ka.NT64, 256, 0, stream>>>(ka);          // layer 0: mean(hb) @ W0 + b0
    k_p6<<<ka.NT64, 256, 0, stream>>>(ka);          // layer 1 fused
    k_p7<<<ka.NT64, 256, 0, stream>>>(ka);          // layer 2 fused
    k_p8<<<ka.NT256, 256, 0, stream>>>(ka);         // transform3 (scalar q)
    k_p9<<<ka.NT256, 256, 0, stream>>>(ka);         // aggregate3 (4B gather)
    k_p10<<<G, 256, 0, stream>>>(ka);               // pool + MLP
}

// Round 9
// 282.858 us; speedup vs baseline: 8.0617x; 1.0414x over previous
//
#include <hip/hip_runtime.h>

#define NSLOT 32
#define BN_EPS 1e-5f
#define NSB 256             // hist/scatter slices
#define BKBITS 8
#define BKN 256             // nodes per bucket
#define MAXBUCK 512

static inline int cdiv_h(int a, int b) { return (a + b - 1) / b; }

__device__ __forceinline__ float4 f4add(float4 a, float4 b) {
    return make_float4(a.x + b.x, a.y + b.y, a.z + b.z, a.w + b.w);
}

__device__ __forceinline__ unsigned bf16rtn(float x) {
    unsigned u = __float_as_uint(x);
    return (u + 0x7FFFu + ((u >> 16) & 1u)) >> 16;
}
__device__ __forceinline__ unsigned bf16pack2(float lo, float hi) {
    return bf16rtn(lo) | (bf16rtn(hi) << 16);
}
__device__ __forceinline__ float bfLO(unsigned u) { return __uint_as_float(u << 16); }
__device__ __forceinline__ float bfHI(unsigned u) { return __uint_as_float(u & 0xFFFF0000u); }

__device__ __forceinline__ int blk_excl_scan256(int v, int t) {
    __shared__ int wsum[4];
    int l = t & 63, w = t >> 6;
    int incl = v;
#pragma unroll
    for (int off = 1; off < 64; off <<= 1) {
        int o = __shfl_up(incl, off, 64);
        if (l >= off) incl += o;
    }
    if (l == 63) wsum[w] = incl;
    __syncthreads();
    int wofs = 0;
#pragma unroll
    for (int i = 0; i < 4; i++) wofs += (i < w) ? wsum[i] : 0;
    __syncthreads();
    return wofs + incl - v;
}

__device__ __forceinline__ void bn_coef(const float* __restrict__ sSum, const float* __restrict__ sSq,
                                        const float* __restrict__ bg, const float* __restrict__ bb,
                                        float invN, int ch, float* aOut, float* cOut) {
    float S = 0.f, Q = 0.f;
#pragma unroll
    for (int s = 0; s < NSLOT; s++) { S += sSum[s * 32 + ch]; Q += sSq[s * 32 + ch]; }
    float m = S * invN;
    float var = Q * invN - m * m;
    if (var < 0.f) var = 0.f;
    float iv = rsqrtf(var + BN_EPS);
    float a = bg[ch] * iv;
    *aOut = a;
    *cOut = bb[ch] - m * a;
}

__device__ __forceinline__ void inline_scan512(const int* __restrict__ tot, int* __restrict__ sOut,
                                               int* __restrict__ sTot, int nbuck, int t) {
    int v0 = (t < nbuck) ? tot[t] : 0;
    int v1 = (256 + t < nbuck) ? tot[256 + t] : 0;
    int e0 = blk_excl_scan256(v0, t);
    if (t == 255) *sTot = e0 + v0;
    __syncthreads();
    int e1 = blk_excl_scan256(v1, t) + *sTot;
    sOut[t] = e0;
    sOut[256 + t] = e1;
    __syncthreads();
}

__device__ __forceinline__ void accPlain(float* dst, uint4 v) {
    dst[0] += bfLO(v.x); dst[1] += bfHI(v.x);
    dst[2] += bfLO(v.y); dst[3] += bfHI(v.y);
    dst[4] += bfLO(v.z); dst[5] += bfHI(v.z);
    dst[6] += bfLO(v.w); dst[7] += bfHI(v.w);
}
__device__ __forceinline__ void accAff(float* dst, uint4 v, const float* a8, const float* c8) {
    float x[8] = { bfLO(v.x), bfHI(v.x), bfLO(v.y), bfHI(v.y),
                   bfLO(v.z), bfHI(v.z), bfLO(v.w), bfHI(v.w) };
#pragma unroll
    for (int q = 0; q < 8; q++) { float r = fmaf(a8[q], x[q], c8[q]); dst[q] += r > 0.f ? r : 0.f; }
}

struct KArgs {
    const float* h; const int* src; const int* dst; const int* gid;
    const float* W0; const float* b0c; const float* W1; const float* b1c;
    const float* W2; const float* b2c; const float* w3; const float* b3c;
    const float* bg0; const float* bb0; const float* bg1; const float* bb1;
    const float* bg2; const float* bb2; const float* bg3; const float* bb3;
    const float* mw0; const float* mb0; const float* mw1; const float* mb1;
    const float* mw2; const float* mb2;
    int* histT; int* prefixB; int* totalP; int* totalU;
    unsigned* ebuf; uint4* pb; int* col; int* rs; int* re; int* gstart;
    uint4* y0b; uint4* y1b; uint4* y2b; float* y3;
    float* sSum; float* sSq; float* out;
    int N, E, G, nbuck, chunk, NT64, NT256;
    float invN;
};

// ---------------- p1: hist slices (bid<NSB) | transform0 pb = bf16(h @ W0) (bid>=NSB) ----------

__global__ __launch_bounds__(256) void k_p1(KArgs a) {
    __shared__ int bins[MAXBUCK];
    __shared__ float sW[32][32];
    int t = threadIdx.x, bid = blockIdx.x;
    if (bid < NSB) {
        if (bid == 0) {
            for (int i = t; i < 4 * NSLOT * 32; i += 256) { a.sSum[i] = 0.f; a.sSq[i] = 0.f; }
        }
        for (int b = t; b < a.nbuck; b += 256) bins[b] = 0;
        __syncthreads();
        int lo = bid * a.chunk, hi = lo + a.chunk; if (hi > a.E) hi = a.E;
        for (int i = lo + t; i < hi; i += 256) atomicAdd(&bins[a.dst[i] >> BKBITS], 1);
        __syncthreads();
        for (int b = t; b < a.nbuck; b += 256) a.histT[bid * a.nbuck + b] = bins[b];
    } else {
        for (int i = t; i < 1024; i += 256) sW[i >> 5][i & 31] = a.W0[i];
        __syncthreads();
        int node = (bid - NSB) * 256 + t;
        if (node >= a.N) return;
        float x[32];
        const float4* s4 = (const float4*)a.h + (size_t)node * 8;
#pragma unroll
        for (int q = 0; q < 8; q++) {
            float4 v = s4[q];
            x[4*q] = v.x; x[4*q+1] = v.y; x[4*q+2] = v.z; x[4*q+3] = v.w;
        }
        float acc[32];
#pragma unroll
        for (int f = 0; f < 32; f++) acc[f] = 0.f;
#pragma unroll
        for (int k = 0; k < 32; k++) {
            float xv = x[k];
#pragma unroll
            for (int f = 0; f < 32; f++) acc[f] += xv * sW[k][f];
        }
        uint4* d4 = a.pb + (size_t)node * 4;
#pragma unroll
        for (int q = 0; q < 4; q++) {
            uint4 o;
            o.x = bf16pack2(acc[8*q+0], acc[8*q+1]);
            o.y = bf16pack2(acc[8*q+2], acc[8*q+3]);
            o.z = bf16pack2(acc[8*q+4], acc[8*q+5]);
            o.w = bf16pack2(acc[8*q+6], acc[8*q+7]);
            d4[q] = o;
        }
    }
}

// ---------------- p2: per-bucket cell scan + gstart ----------------

__global__ __launch_bounds__(256) void k_p2(KArgs a) {
    int b = blockIdx.x, t = threadIdx.x;
    int i = b * 256 + t;
    if (i < a.N) {
        int g = a.gid[i];
        int gp = (i == 0) ? -1 : a.gid[i - 1];
        for (int x = gp + 1; x <= g; ++x) a.gstart[x] = i;
        if (i == a.N - 1) { for (int x = g + 1; x <= a.G; ++x) a.gstart[x] = a.N; }
    }
    int c = a.histT[t * a.nbuck + b];
    int pad = (c + 15) & ~15;
    int ep = blk_excl_scan256(pad, t);
    a.prefixB[b * NSB + t] = ep;
    int ec = blk_excl_scan256(c, t);
    if (t == NSB - 1) { a.totalP[b] = ep + pad; a.totalU[b] = ec + c; }
}

// ---------------- p3: deterministic scatter (LDS cursors, inline cross-bucket scan) ------------

__global__ __launch_bounds__(256) void k_p3(KArgs a) {
    __shared__ int sBP[512];
    __shared__ int sTot;
    __shared__ int cur[MAXBUCK];
    int bid = blockIdx.x, t = threadIdx.x;
    inline_scan512(a.totalP, sBP, &sTot, a.nbuck, t);
    for (int b = t; b < a.nbuck; b += 256) cur[b] = sBP[b] + a.prefixB[b * NSB + bid];
    __syncthreads();
    int lo = bid * a.chunk, hi = lo + a.chunk; if (hi > a.E) hi = a.E;
    for (int i = lo + t; i < hi; i += 256) {
        int d = a.dst[i], s = a.src[i];
        int b = d >> BKBITS;
        int pos = atomicAdd(&cur[b], 1);
        a.ebuf[pos] = ((unsigned)(d & (BKN - 1)) << 24) | (unsigned)s;
    }
}

// ---------------- p4: per-bucket counting sort -> col/rs/re ----------------

__global__ __launch_bounds__(256) void k_p4(KArgs a) {
    __shared__ int sBP[512];
    __shared__ int sTot;
    __shared__ int binCnt[BKN], binStart[BKN], cursor[BKN];
    __shared__ int cellBase[NSB], cellCnt[NSB];
    int b = blockIdx.x, t = threadIdx.x;
    inline_scan512(a.totalP, sBP, &sTot, a.nbuck, t);
    int basePb = sBP[b];
    __syncthreads();
    inline_scan512(a.totalU, sBP, &sTot, a.nbuck, t);
    int baseUb = sBP[b];
    cellBase[t] = basePb + a.prefixB[b * NSB + t];
    cellCnt[t]  = a.histT[t * a.nbuck + b];
    binCnt[t] = 0; cursor[t] = 0;
    __syncthreads();
    {
        int cb = cellBase[t], cc = cellCnt[t];
        for (int j = 0; j < cc; j++) atomicAdd(&binCnt[a.ebuf[cb + j] >> 24], 1);
    }
    __syncthreads();
    int bs = blk_excl_scan256(binCnt[t], t);
    binStart[t] = bs;
    __syncthreads();
    {
        int cb = cellBase[t], cc = cellCnt[t];
        for (int j = 0; j < cc; j++) {
            unsigned e = a.ebuf[cb + j];
            int l = e >> 24;
            int pos = binStart[l] + atomicAdd(&cursor[l], 1);
            a.col[baseUb + pos] = (int)(e & 0xFFFFFFu);
        }
    }
    int node = b * BKN + t;
    if (node < a.N) {
        a.rs[node] = baseUb + binStart[t];
        a.re[node] = baseUb + binStart[t] + binCnt[t];
    }
}

// ---------------- p5: layer-0 aggregate (plain mean of pb + bias), high occupancy --------------

__global__ __launch_bounds__(256, 6) void k_p5(KArgs a) {
    __shared__ int scol[2048];
    __shared__ float sWS[4][32];
    __shared__ float sWQ[4][32];
    int t = threadIdx.x;
    int lane = t & 3, grp = t >> 2;
    int node0 = blockIdx.x * 64, node = node0 + grp;
    int base0 = 0, len = 0;
    if (node0 < a.N) {
        int last = node0 + 63; if (last > a.N - 1) last = a.N - 1;
        base0 = a.rs[node0];
        len = a.re[last] - base0;
    }
    bool lds = (len > 0 && len <= 2048);
    if (lds) { for (int i = t; i < len; i += 256) scol[i] = a.col[base0 + i]; }
    __syncthreads();

    float accA[8], accB[8];
#pragma unroll
    for (int q = 0; q < 8; q++) { accA[q] = 0.f; accB[q] = 0.f; }
    float vout[8];
#pragma unroll
    for (int q = 0; q < 8; q++) vout[q] = 0.f;
    if (node < a.N) {
        int s0 = a.rs[node], s1 = a.re[node];
#define GATH2(vv, c) vv = a.pb[(size_t)(c) * 4 + lane]
        const int* idx = lds ? scol : a.col;
        int j = lds ? s0 - base0 : s0;
        int j1 = lds ? s1 - base0 : s1;
        if (j + 4 <= j1) {
            uint4 g0, g1, g2, g3;
            GATH2(g0, idx[j]); GATH2(g1, idx[j + 1]); GATH2(g2, idx[j + 2]); GATH2(g3, idx[j + 3]);
            j += 4;
            for (; j + 4 <= j1; j += 4) {
                uint4 h0, h1, h2, h3;
                GATH2(h0, idx[j]); GATH2(h1, idx[j + 1]); GATH2(h2, idx[j + 2]); GATH2(h3, idx[j + 3]);
                accPlain(accA, g0); accPlain(accB, g1); accPlain(accA, g2); accPlain(accB, g3);
                g0 = h0; g1 = h1; g2 = h2; g3 = h3;
            }
            accPlain(accA, g0); accPlain(accB, g1); accPlain(accA, g2); accPlain(accB, g3);
        }
        for (; j < j1; ++j) { uint4 g; GATH2(g, idx[j]); accPlain(accA, g); }
#undef GATH2
        int deg = s1 - s0;
        float inv = (deg > 0) ? 1.f / (float)deg : 1.f;
        const float4* b4 = (const float4*)a.b0c;
        float4 b0 = b4[lane * 2], b1 = b4[lane * 2 + 1];
        vout[0] = (accA[0] + accB[0]) * inv + b0.x;
        vout[1] = (accA[1] + accB[1]) * inv + b0.y;
        vout[2] = (accA[2] + accB[2]) * inv + b0.z;
        vout[3] = (accA[3] + accB[3]) * inv + b0.w;
        vout[4] = (accA[4] + accB[4]) * inv + b1.x;
        vout[5] = (accA[5] + accB[5]) * inv + b1.y;
        vout[6] = (accA[6] + accB[6]) * inv + b1.z;
        vout[7] = (accA[7] + accB[7]) * inv + b1.w;
        uint4 o;
        o.x = bf16pack2(vout[0], vout[1]);
        o.y = bf16pack2(vout[2], vout[3]);
        o.z = bf16pack2(vout[4], vout[5]);
        o.w = bf16pack2(vout[6], vout[7]);
        a.y0b[(size_t)node * 4 + lane] = o;
    }
    float sqv[8];
#pragma unroll
    for (int q = 0; q < 8; q++) sqv[q] = vout[q] * vout[q];
#pragma unroll
    for (int off = 4; off < 64; off <<= 1) {
#pragma unroll
        for (int q = 0; q < 8; q++) {
            vout[q] += __shfl_xor(vout[q], off, 64);
            sqv[q]  += __shfl_xor(sqv[q],  off, 64);
        }
    }
    int w = t >> 6, l = t & 63;
    if (l < 4) {
#pragma unroll
        for (int q = 0; q < 8; q++) { sWS[w][l * 8 + q] = vout[q]; sWQ[w][l * 8 + q] = sqv[q]; }
    }
    __syncthreads();
    if (t < 32) {
        float S = sWS[0][t] + sWS[1][t] + sWS[2][t] + sWS[3][t];
        float Q = sWQ[0][t] + sWQ[1][t] + sWQ[2][t] + sWQ[3][t];
        int slot = blockIdx.x & (NSLOT - 1);
        atomicAdd(&a.sSum[slot * 32 + t], S);
        atomicAdd(&a.sSq[slot * 32 + t], Q);
    }
}

// ---------------- p6/p7: fused layers 1/2 (affine+relu per edge, mean, @W epilogue) ------------

__device__ __forceinline__ void aggF_kernel(const KArgs& a, const uint4* yin, uint4* yout,
                                            const float* W, const float* bias,
                                            const float* pSum, const float* pSq,
                                            const float* bg, const float* bb,
                                            float* oSum, float* oSq) {
    __shared__ int scol[2112];
    __shared__ float sW[32][32];
    __shared__ float sA[32], sC[32];
    __shared__ float sWS[4][32];
    __shared__ float sWQ[4][32];
    int t = threadIdx.x;
    for (int i = t; i < 1024; i += 256) sW[i >> 5][i & 31] = W[i];
    if (t < 32) bn_coef(pSum, pSq, bg, bb, a.invN, t, &sA[t], &sC[t]);
    int lane = t & 3, grp = t >> 2;
    int node0 = blockIdx.x * 64, node = node0 + grp;
    int base0 = 0, len = 0;
    if (node0 < a.N) {
        int last = node0 + 63; if (last > a.N - 1) last = a.N - 1;
        base0 = a.rs[node0];
        len = a.re[last] - base0;
    }
    bool lds = (len > 0 && len <= 2048);
    __syncthreads();                        // sA/sC/sW ready
    if (lds) { for (int i = t; i < len; i += 256) scol[i] = a.col[base0 + i]; }
    __syncthreads();
    float a8[8], c8[8];
#pragma unroll
    for (int q = 0; q < 8; q++) { a8[q] = sA[lane * 8 + q]; c8[q] = sC[lane * 8 + q]; }

    float accA[8], accB[8];
#pragma unroll
    for (int q = 0; q < 8; q++) { accA[q] = 0.f; accB[q] = 0.f; }
    float vout[8];
#pragma unroll
    for (int q = 0; q < 8; q++) vout[q] = 0.f;
    int s0 = 0, s1 = 0;
    if (node < a.N) {
        s0 = a.rs[node]; s1 = a.re[node];
#define GATH2(vv, c) vv = yin[(size_t)(c) * 4 + lane]
        const int* idx = lds ? scol : a.col;
        int j = lds ? s0 - base0 : s0;
        int j1 = lds ? s1 - base0 : s1;
        if (j + 4 <= j1) {
            uint4 g0, g1, g2, g3;
            GATH2(g0, idx[j]); GATH2(g1, idx[j + 1]); GATH2(g2, idx[j + 2]); GATH2(g3, idx[j + 3]);
            j += 4;
            for (; j + 4 <= j1; j += 4) {
                uint4 h0, h1, h2, h3;
                GATH2(h0, idx[j]); GATH2(h1, idx[j + 1]); GATH2(h2, idx[j + 2]); GATH2(h3, idx[j + 3]);
                accAff(accA, g0, a8, c8); accAff(accB, g1, a8, c8);
                accAff(accA, g2, a8, c8); accAff(accB, g3, a8, c8);
                g0 = h0; g1 = h1; g2 = h2; g3 = h3;
            }
            accAff(accA, g0, a8, c8); accAff(accB, g1, a8, c8);
            accAff(accA, g2, a8, c8); accAff(accB, g3, a8, c8);
        }
        for (; j < j1; ++j) { uint4 g; GATH2(g, idx[j]); accAff(accA, g, a8, c8); }
#undef GATH2
    }
    // mean -> LDS (scol overlay; all gathers done), then @W epilogue
    float* sM = (float*)scol;
    __syncthreads();
    if (node < a.N) {
        int deg = s1 - s0;
        float inv = (deg > 0) ? 1.f / (float)deg : 1.f;
#pragma unroll
        for (int q = 0; q < 8; q++) sM[grp * 33 + lane * 8 + q] = (accA[q] + accB[q]) * inv;
    }
    __syncthreads();
    if (node < a.N) {
        const float4* b4 = (const float4*)bias;
        float4 b0 = b4[lane * 2], b1 = b4[lane * 2 + 1];
        float outv[8] = { b0.x, b0.y, b0.z, b0.w, b1.x, b1.y, b1.z, b1.w };
#pragma unroll
        for (int k = 0; k < 32; k++) {
            float mk = sM[grp * 33 + k];
#pragma unroll
            for (int q = 0; q < 8; q++) outv[q] += mk * sW[k][lane * 8 + q];
        }
#pragma unroll
        for (int q = 0; q < 8; q++) vout[q] = outv[q];
        uint4 o;
        o.x = bf16pack2(vout[0], vout[1]);
        o.y = bf16pack2(vout[2], vout[3]);
        o.z = bf16pack2(vout[4], vout[5]);
        o.w = bf16pack2(vout[6], vout[7]);
        yout[(size_t)node * 4 + lane] = o;
    }
    float sqv[8];
#pragma unroll
    for (int q = 0; q < 8; q++) sqv[q] = vout[q] * vout[q];
#pragma unroll
    for (int off = 4; off < 64; off <<= 1) {
#pragma unroll
        for (int q = 0; q < 8; q++) {
            vout[q] += __shfl_xor(vout[q], off, 64);
            sqv[q]  += __shfl_xor(sqv[q],  off, 64);
        }
    }
    int w = t >> 6, l = t & 63;
    if (l < 4) {
#pragma unroll
        for (int q = 0; q < 8; q++) { sWS[w][l * 8 + q] = vout[q]; sWQ[w][l * 8 + q] = sqv[q]; }
    }
    __syncthreads();
    if (t < 32) {
        float S = sWS[0][t] + sWS[1][t] + sWS[2][t] + sWS[3][t];
        float Q = sWQ[0][t] + sWQ[1][t] + sWQ[2][t] + sWQ[3][t];
        int slot = blockIdx.x & (NSLOT - 1);
        atomicAdd(&oSum[slot * 32 + t], S);
        atomicAdd(&oSq[slot * 32 + t], Q);
    }
}

__global__ __launch_bounds__(256, 5) void k_p6(KArgs a) {
    aggF_kernel(a, a.y0b, a.y1b, a.W1, a.b1c,
                a.sSum + 0 * NSLOT * 32, a.sSq + 0 * NSLOT * 32, a.bg0, a.bb0,
                a.sSum + 1 * NSLOT * 32, a.sSq + 1 * NSLOT * 32);
}
__global__ __launch_bounds__(256, 5) void k_p7(KArgs a) {
    aggF_kernel(a, a.y1b, a.y2b, a.W2, a.b2c,
                a.sSum + 1 * NSLOT * 32, a.sSq + 1 * NSLOT * 32, a.bg1, a.bb1,
                a.sSum + 2 * NSLOT * 32, a.sSq + 2 * NSLOT * 32);
}

// ---------------- p8: transform3 q[v] = relu(a*y2+c) . w3 (scalar per node) ----------------

__global__ __launch_bounds__(256) void k_p8(KArgs a) {
    __shared__ float sw[32], sA[32], sC[32];
    int t = threadIdx.x;
    float* q = (float*)a.pb;         // pb dead after p5
    if (t < 32) {
        sw[t] = a.w3[t];
        bn_coef(a.sSum + 2 * NSLOT * 32, a.sSq + 2 * NSLOT * 32, a.bg2, a.bb2,
                a.invN, t, &sA[t], &sC[t]);
    }
    __syncthreads();
    int i = blockIdx.x * 256 + t;
    if (i < a.N) {
        const uint4* x4 = a.y2b + (size_t)i * 4;
        float acc = 0.f;
#pragma unroll
        for (int qq = 0; qq < 4; qq++) {
            uint4 u = x4[qq];
            float vv[8] = { bfLO(u.x), bfHI(u.x), bfLO(u.y), bfHI(u.y),
                            bfLO(u.z), bfHI(u.z), bfLO(u.w), bfHI(u.w) };
#pragma unroll
            for (int r = 0; r < 8; r++) {
                int k = qq * 8 + r;
                float xv = sA[k] * vv[r] + sC[k];
                xv = xv > 0.f ? xv : 0.f;
                acc += xv * sw[k];
            }
        }
        q[i] = acc;
    }
}

// ---------------- p9: aggregate3 (4B scalar gather) + BN3 stats ----------------

__global__ __launch_bounds__(256) void k_p9(KArgs a) {
    __shared__ float sWS3[4], sWQ3[4];
    const float* q = (const float*)a.pb;
    int t = threadIdx.x;
    int i = blockIdx.x * 256 + t;
    float lsum = 0.f, lsq = 0.f;
    if (i < a.N) {
        int s0 = a.rs[i], s1 = a.re[i];
        float a0 = 0.f, a1 = 0.f, a2 = 0.f, a3 = 0.f;
        int j = s0;
        if (j + 4 <= s1) {
            float g0 = q[a.col[j]], g1 = q[a.col[j+1]], g2 = q[a.col[j+2]], g3 = q[a.col[j+3]];
            j += 4;
            for (; j + 4 <= s1; j += 4) {
                float h0 = q[a.col[j]], h1 = q[a.col[j+1]], h2 = q[a.col[j+2]], h3 = q[a.col[j+3]];
                a0 += g0; a1 += g1; a2 += g2; a3 += g3;
                g0 = h0; g1 = h1; g2 = h2; g3 = h3;
            }
            a0 += g0; a1 += g1; a2 += g2; a3 += g3;
        }
        for (; j < s1; ++j) a0 += q[a.col[j]];
        float acc = (a0 + a1) + (a2 + a3);
        float inv = (s1 > s0) ? 1.f / (float)(s1 - s0) : 1.f;
        float v = acc * inv + a.b3c[0];
        a.y3[i] = v; lsum = v; lsq = v * v;
    }
#pragma unroll
    for (int off = 1; off < 64; off <<= 1) {
        lsum += __shfl_xor(lsum, off, 64);
        lsq  += __shfl_xor(lsq,  off, 64);
    }
    if ((t & 63) == 0) { sWS3[t >> 6] = lsum; sWQ3[t >> 6] = lsq; }
    __syncthreads();
    if (t == 0) {
        float S = sWS3[0] + sWS3[1] + sWS3[2] + sWS3[3];
        float Q = sWQ3[0] + sWQ3[1] + sWQ3[2] + sWQ3[3];
        int slot = blockIdx.x & (NSLOT - 1);
        atomicAdd(&a.sSum[3 * NSLOT * 32 + slot * 32], S);
        atomicAdd(&a.sSq[3 * NSLOT * 32 + slot * 32], Q);
    }
}

// ---------------- p10: per-graph mean pool + MLP ----------------

__global__ __launch_bounds__(256) void k_p10(KArgs a) {
    __shared__ float pcA[128], pcC[128];
    __shared__ float sP[8][128];
    __shared__ float sY[4];
    __shared__ float hg[129];
    __shared__ float hid1[128];
    __shared__ float hid2[64];
    int g = blockIdx.x;
    int t = threadIdx.x;
    if (t < 97) {
        int layer = (t == 96) ? 3 : (t >> 5);
        int ch = t & 31;
        const float* bg = (layer == 0) ? a.bg0 : (layer == 1) ? a.bg1 : (layer == 2) ? a.bg2 : a.bg3;
        const float* bb = (layer == 0) ? a.bb0 : (layer == 1) ? a.bb1 : (layer == 2) ? a.bb2 : a.bb3;
        bn_coef(a.sSum + layer * NSLOT * 32, a.sSq + layer * NSLOT * 32, bg, bb, a.invN, ch,
                &pcA[t], &pcC[t]);
    }
    __syncthreads();
    int s0 = a.gstart[g], s1 = a.gstart[g + 1];
    int lane = t & 31, slot = t >> 5;
    int arr = lane >> 3, sub = lane & 7;
    const unsigned* yb = (arr == 1) ? (const unsigned*)a.y0b
                       : (arr == 2) ? (const unsigned*)a.y1b : (const unsigned*)a.y2b;
    float4 a4 = make_float4(1.f, 1.f, 1.f, 1.f);
    float4 c4 = make_float4(0.f, 0.f, 0.f, 0.f);
    bool aff = (arr > 0);
    if (aff) {
        a4 = ((const float4*)pcA)[(arr - 1) * 8 + sub];
        c4 = ((const float4*)pcC)[(arr - 1) * 8 + sub];
    }
    float4 acc = make_float4(0.f, 0.f, 0.f, 0.f);
    for (int n = s0 + slot; n < s1; n += 8) {
        float4 v;
        if (arr == 0) {
            v = ((const float4*)a.h)[(size_t)n * 8 + sub];
        } else {
            uint2 u = ((const uint2*)yb)[(size_t)n * 8 + sub];
            v = make_float4(bfLO(u.x), bfHI(u.x), bfLO(u.y), bfHI(u.y));
        }
        if (aff) {
            float vx = fmaf(a4.x, v.x, c4.x); vx = vx > 0.f ? vx : 0.f;
            float vy = fmaf(a4.y, v.y, c4.y); vy = vy > 0.f ? vy : 0.f;
            float vz = fmaf(a4.z, v.z, c4.z); vz = vz > 0.f ? vz : 0.f;
            float vw = fmaf(a4.w, v.w, c4.w); vw = vw > 0.f ? vw : 0.f;
            v = make_float4(vx, vy, vz, vw);
        }
        acc = f4add(acc, v);
    }
    float ys = 0.f;
    {
        float aY = pcA[96], cY = pcC[96];
        for (int n = s0 + t; n < s1; n += 256) {
            float v = fmaf(aY, a.y3[n], cY);
            ys += v > 0.f ? v : 0.f;
        }
    }
#pragma unroll
    for (int off = 1; off < 64; off <<= 1) ys += __shfl_xor(ys, off, 64);
    if ((t & 63) == 0) sY[t >> 6] = ys;
    ((float4*)&sP[slot][lane * 4])[0] = acc;
    __syncthreads();
    float inv = (s1 > s0) ? 1.f / (float)(s1 - s0) : 1.f;
    if (t < 128) {
        float S = 0.f;
#pragma unroll
        for (int s = 0; s < 8; s++) S += sP[s][t];
        hg[t] = S * inv;
    } else if (t == 128) {
        float S = sY[0] + sY[1] + sY[2] + sY[3];
        hg[128] = S * inv;
    }
    __syncthreads();
    if (t < 128) {
        float v = a.mb0[t];
        for (int i = 0; i < 129; i++) v += hg[i] * a.mw0[i * 128 + t];
        hid1[t] = v > 0.f ? v : 0.f;
    }
    __syncthreads();
    if (t < 64) {
        float v = a.mb1[t];
        for (int i = 0; i < 128; i++) v += hid1[i] * a.mw1[i * 64 + t];
        hid2[t] = v > 0.f ? v : 0.f;
    }
    __syncthreads();
    if (t < 64) {
        float v = hid2[t] * a.mw2[t];
        for (int off = 32; off > 0; off >>= 1) v += __shfl_down(v, off, 64);
        if (t == 0) a.out[g] = v + a.mb2[0];
    }
}

// ---------------- launcher (10 dispatches) ----------------

extern "C" void kernel_launch(void* const* d_in, const int* in_sizes, int n_in,
                              void* d_out, int out_size, void* d_ws, size_t ws_size,
                              hipStream_t stream) {
    KArgs ka;
    ka.h   = (const float*)d_in[0];
    ka.src = (const int*)d_in[1];
    ka.dst = (const int*)d_in[2];
    ka.gid = (const int*)d_in[3];
    const float* convw[4], *convb[4], *bng[4], *bnb[4];
    for (int i = 0; i < 4; i++) {
        convw[i] = (const float*)d_in[4 + 4 * i];
        convb[i] = (const float*)d_in[5 + 4 * i];
        bng[i]   = (const float*)d_in[6 + 4 * i];
        bnb[i]   = (const float*)d_in[7 + 4 * i];
    }
    ka.W0 = convw[0]; ka.b0c = convb[0]; ka.W1 = convw[1]; ka.b1c = convb[1];
    ka.W2 = convw[2]; ka.b2c = convb[2]; ka.w3 = convw[3]; ka.b3c = convb[3];
    ka.bg0 = bng[0]; ka.bb0 = bnb[0]; ka.bg1 = bng[1]; ka.bb1 = bnb[1];
    ka.bg2 = bng[2]; ka.bb2 = bnb[2]; ka.bg3 = bng[3]; ka.bb3 = bnb[3];
    ka.mw0 = (const float*)d_in[20]; ka.mb0 = (const float*)d_in[21];
    ka.mw1 = (const float*)d_in[22]; ka.mb1 = (const float*)d_in[23];
    ka.mw2 = (const float*)d_in[24]; ka.mb2 = (const float*)d_in[25];

    const int N = in_sizes[0] / 32;
    const int E = in_sizes[1];
    const int G = out_size;
    const int nbuck = cdiv_h(N, BKN);
    const int chunk = cdiv_h(E, NSB);

    char* ws = (char*)d_ws;
    size_t off = 0;
    auto alloc = [&](size_t bytes) -> void* {
        void* p = ws + off;
        off += (bytes + 511) & ~(size_t)511;
        return p;
    };
    ka.histT   = (int*)alloc((size_t)NSB * nbuck * 4);
    ka.prefixB = (int*)alloc((size_t)nbuck * NSB * 4);
    ka.totalP  = (int*)alloc((size_t)nbuck * 4);
    ka.totalU  = (int*)alloc((size_t)nbuck * 4);
    size_t ebufE = (size_t)E + (size_t)16 * NSB * nbuck;
    ka.ebuf = (unsigned*)alloc(ebufE * 4);
    ka.pb   = (uint4*)alloc((size_t)N * 64);     // bf16 p (layer0); reused as fp32 q in p8/p9
    ka.col  = (int*)alloc((size_t)E * 4);
    ka.rs   = (int*)alloc((size_t)N * 4);
    ka.re   = (int*)alloc((size_t)N * 4);
    ka.gstart = (int*)alloc((size_t)(G + 1) * 4);
    ka.y0b  = (uint4*)alloc((size_t)N * 64);
    ka.y1b  = (uint4*)alloc((size_t)N * 64);
    ka.y2b  = (uint4*)alloc((size_t)N * 64);
    ka.y3   = (float*)alloc((size_t)N * 4);
    ka.sSum = (float*)alloc((size_t)4 * NSLOT * 32 * 4);
    ka.sSq  = (float*)alloc((size_t)4 * NSLOT * 32 * 4);
    ka.out  = (float*)d_out;
    (void)ws_size; (void)n_in;

    ka.N = N; ka.E = E; ka.G = G; ka.nbuck = nbuck; ka.chunk = chunk;
    ka.NT64 = cdiv_h(N, 64); ka.NT256 = cdiv_h(N, 256);
    ka.invN = 1.f / (float)N;

    k_p1<<<NSB + ka.NT256, 256, 0, stream>>>(ka);   // hist + transform0 -> pb
    k_p2<<<nbuck, 256, 0, stream>>>(ka);            // cell scan + gstart
    k_p3<<<NSB, 256, 0, stream>>>(ka);              // deterministic scatter
    k_p4<<<nbuck, 256, 0, stream>>>(ka);            // counting sort -> col/rs/re
    k_p5<<<ka.NT64, 256, 0, stream>>>(ka);          // layer 0: mean(pb) + b0
    k_p6<<<ka.NT64, 256, 0, stream>>>(ka);          // layer 1 fused
    k_p7<<<ka.NT64, 256, 0, stream>>>(ka);          // layer 2 fused
    k_p8<<<ka.NT256, 256, 0, stream>>>(ka);         // transform3 (scalar q)
    k_p9<<<ka.NT256, 256, 0, stream>>>(ka);         // aggregate3 (4B gather)
    k_p10<<<G, 256, 0, stream>>>(ka);               // pool + MLP
}